// Round 1
// baseline (765.531 us; speedup 1.0000x reference)
//
#include <hip/hip_runtime.h>
#include <cstdint>
#include <cstddef>

// ---------------------------------------------------------------------------
// Mamba-style prelude block on MI355X (gfx950).
// Pipeline: rmsnorm -> (in_proj, gate_proj) GEMM -> z*sigmoid(gate)
//   -> dt GEMM (+softplus bias) -> x_proj (small GEMM) -> selective scan
//   -> out_proj GEMM (+residual) -> rmsnorm -> (ffn gate/up) GEMM
//   -> silu(g)*u -> ffn down GEMM (+residual) -> d_out
// All big GEMMs: bf16 MFMA (m97 pattern: 128x128 tile, BK=32,
// global_load_lds width=16, mfma_f32_16x16x32_bf16).
// ---------------------------------------------------------------------------

#define BM 128
#define BN 128
#define BK 32

typedef __attribute__((ext_vector_type(8))) short short8;   // 8 bf16 (4 VGPRs)
typedef __attribute__((ext_vector_type(4))) float floatx4;  // 4 fp32 acc

__device__ __forceinline__ unsigned short f2bf(float f) {
  unsigned int u = __builtin_bit_cast(unsigned int, f);
  u = u + 0x7fffu + ((u >> 16) & 1u);   // round-to-nearest-even
  return (unsigned short)(u >> 16);
}

__device__ __forceinline__ void async_copy16(const unsigned short* g, unsigned short* l) {
  __builtin_amdgcn_global_load_lds(
      (__attribute__((address_space(1))) void*)(const_cast<unsigned short*>(g)),
      (__attribute__((address_space(3))) void*)(l), 16, 0, 0);
}

// ---------------------------------------------------------------------------
// fp32 -> bf16 weight conversion with optional row padding (zeros).
// Grid-stride over dst_rows*cols4 float4 groups.
// ---------------------------------------------------------------------------
__global__ void cvt_bf16(const float* __restrict__ src, unsigned short* __restrict__ dst,
                         int rows, int cols4, int dst_rows) {
  int i = blockIdx.x * blockDim.x + threadIdx.x;
  int total = dst_rows * cols4;
  if (i >= total) return;
  int r = i / cols4, c = i - r * cols4;
  ushort4 o = {0, 0, 0, 0};
  if (r < rows) {
    float4 v = *(const float4*)&src[((size_t)r * cols4 + c) * 4];
    o.x = f2bf(v.x); o.y = f2bf(v.y); o.z = f2bf(v.z); o.w = f2bf(v.w);
  }
  *(ushort4*)&dst[((size_t)r * cols4 + c) * 4] = o;
}

// ---------------------------------------------------------------------------
// RMSNorm: one block (256 thr) per row of D=1024 fp32, writes bf16.
// ---------------------------------------------------------------------------
__global__ __launch_bounds__(256) void rmsnorm_bf16(
    const float* __restrict__ x, const float* __restrict__ w,
    unsigned short* __restrict__ out) {
  const int D = 1024;
  int row = blockIdx.x;
  int t = threadIdx.x;
  const float* xr = x + (size_t)row * D;
  float4 v = *(const float4*)&xr[t * 4];
  float ss = v.x * v.x + v.y * v.y + v.z * v.z + v.w * v.w;
#pragma unroll
  for (int m = 1; m < 64; m <<= 1) ss += __shfl_xor(ss, m);
  __shared__ float ws_[4];
  if ((t & 63) == 0) ws_[t >> 6] = ss;
  __syncthreads();
  float tot = ws_[0] + ws_[1] + ws_[2] + ws_[3];
  float scale = rsqrtf(tot * (1.0f / D) + 1e-6f);
  ushort4 o;
  o.x = f2bf(v.x * scale * w[t * 4 + 0]);
  o.y = f2bf(v.y * scale * w[t * 4 + 1]);
  o.z = f2bf(v.z * scale * w[t * 4 + 2]);
  o.w = f2bf(v.w * scale * w[t * 4 + 3]);
  *(ushort4*)&out[(size_t)row * D + t * 4] = o;
}

// ---------------------------------------------------------------------------
// bf16 MFMA GEMM, C = A @ W^T (W rows = output features, both row-major, K contig).
// 128x128 tile, BK=32, 4 waves in 2x2, each wave 64x64 (4x4 of 16x16x32 MFMA).
// Two weight pointers for stacked-N launches (bn < n1_blocks -> W1 else W2).
// EPI: 0 = plain store, 1 = softplus(acc + bias[col]), 2 = acc + res[row][col].
// ---------------------------------------------------------------------------
template <int EPI>
__global__ __launch_bounds__(256, 2) void gemm_bt(
    const unsigned short* __restrict__ A,   // M x K bf16
    const unsigned short* __restrict__ W1,  // N1 x K bf16
    const unsigned short* __restrict__ W2,  // N2 x K bf16
    int n1_blocks, int K,
    float* __restrict__ C, int ldc,
    const float* __restrict__ aux) {
  __shared__ __align__(16) unsigned short As[BM * BK];
  __shared__ __align__(16) unsigned short Bs[BN * BK];
  const int tid = threadIdx.x;
  const int wave = tid >> 6, lane = tid & 63;
  const int bn = blockIdx.x, bm = blockIdx.y;
  const unsigned short* W;
  int wrow0;
  if (bn < n1_blocks) { W = W1; wrow0 = bn * BN; }
  else                { W = W2; wrow0 = (bn - n1_blocks) * BN; }
  const int m0 = bm * BM;
  const int wm = wave >> 1, wn = wave & 1;
  const int l15 = lane & 15, quad = lane >> 4;

  floatx4 acc[4][4] = {};

  // staging chunks: 512 x 16B per tile; each thread owns chunks c0 and c0+256.
  // LDS dest must be wave-uniform base + lane*16 -> chunk id = wave*64+lane.
  const int c0 = wave * 64 + lane;
  const int r0 = c0 >> 2, k0off = (c0 & 3) * 8;
  const int c1 = c0 + 256;
  const int r1 = c1 >> 2, k1off = (c1 & 3) * 8;

  const int nk = K / BK;
  for (int kt = 0; kt < nk; ++kt) {
    __syncthreads();  // protect LDS (prev iter ds_reads drained by barrier)
    const int kb = kt * BK;
    async_copy16(A + (size_t)(m0 + r0) * K + kb + k0off, &As[c0 * 8]);
    async_copy16(A + (size_t)(m0 + r1) * K + kb + k1off, &As[c1 * 8]);
    async_copy16(W + (size_t)(wrow0 + r0) * K + kb + k0off, &Bs[c0 * 8]);
    async_copy16(W + (size_t)(wrow0 + r1) * K + kb + k1off, &Bs[c1 * 8]);
    __syncthreads();  // vmcnt(0) drained before barrier by compiler

    short8 af[4], bf[4];
#pragma unroll
    for (int i = 0; i < 4; ++i)
      af[i] = *(const short8*)&As[(wm * 64 + i * 16 + l15) * BK + quad * 8];
#pragma unroll
    for (int j = 0; j < 4; ++j)
      bf[j] = *(const short8*)&Bs[(wn * 64 + j * 16 + l15) * BK + quad * 8];
#pragma unroll
    for (int i = 0; i < 4; ++i)
#pragma unroll
      for (int j = 0; j < 4; ++j)
        acc[i][j] = __builtin_amdgcn_mfma_f32_16x16x32_bf16(af[i], bf[j], acc[i][j], 0, 0, 0);
  }

  // epilogue: D[row=quad*4+r][col=lane&15] per 16x16 tile (verified layout)
#pragma unroll
  for (int i = 0; i < 4; ++i)
#pragma unroll
    for (int j = 0; j < 4; ++j)
#pragma unroll
      for (int r = 0; r < 4; ++r) {
        int gr = m0 + wm * 64 + i * 16 + quad * 4 + r;
        int gc = bn * BN + wn * 64 + j * 16 + l15;
        float v = acc[i][j][r];
        if (EPI == 1) {  // dt: softplus(acc + dt_b[col])
          v += aux[gc];
          v = fmaxf(v, 0.0f) + log1pf(__expf(-fabsf(v)));
        } else if (EPI == 2) {  // residual add
          v += aux[(size_t)gr * ldc + gc];
        }
        C[(size_t)gr * ldc + gc] = v;
      }
}

// ---------------------------------------------------------------------------
// z = z_raw * sigmoid(gate_raw); writes fp32 (for scan) + bf16 (for dt GEMM).
// zg layout: [2048][4096], z cols 0..2047, gate cols 2048..4095.
// ---------------------------------------------------------------------------
__global__ void zfuse(const float* __restrict__ zg, float* __restrict__ z32,
                      unsigned short* __restrict__ zbf) {
  int i = blockIdx.x * blockDim.x + threadIdx.x;  // over 2048*512 float4 groups
  int row = i >> 9, c4 = i & 511;
  float4 zr = *(const float4*)&zg[(size_t)row * 4096 + c4 * 4];
  float4 gr = *(const float4*)&zg[(size_t)row * 4096 + 2048 + c4 * 4];
  float4 o;
  o.x = zr.x / (1.0f + __expf(-gr.x));
  o.y = zr.y / (1.0f + __expf(-gr.y));
  o.z = zr.z / (1.0f + __expf(-gr.z));
  o.w = zr.w / (1.0f + __expf(-gr.w));
  *(float4*)&z32[(size_t)row * 2048 + c4 * 4] = o;
  ushort4 ob;
  ob.x = f2bf(o.x); ob.y = f2bf(o.y); ob.z = f2bf(o.z); ob.w = f2bf(o.w);
  *(ushort4*)&zbf[(size_t)row * 2048 + c4 * 4] = ob;
}

// ---------------------------------------------------------------------------
// BC = z @ x_proj^T  (M=2048, N=32, K=2048, fp32). Block = 8 rows x 32 cols.
// ---------------------------------------------------------------------------
__global__ __launch_bounds__(256) void xproj(const float* __restrict__ z,
                                             const float* __restrict__ xw,
                                             float* __restrict__ bc) {
  int r = threadIdx.x >> 5, n = threadIdx.x & 31;
  int row = blockIdx.x * 8 + r;
  const float4* zp = (const float4*)(z + (size_t)row * 2048);
  const float4* wp = (const float4*)(xw + (size_t)n * 2048);
  float acc = 0.0f;
#pragma unroll 4
  for (int k = 0; k < 512; ++k) {
    float4 a = zp[k], b = wp[k];
    acc += a.x * b.x + a.y * b.y + a.z * b.z + a.w * b.w;
  }
  bc[(size_t)row * 32 + n] = acc;
}

// ---------------------------------------------------------------------------
// Selective scan. lane <-> (b, d, n): 2*2048*16 = 65536 lanes, 16-lane groups
// share a (b,d) channel, butterfly-reduce over n for y. Unroll-4 prefetch.
// h_t = exp(dt*A[d][n]) * h_{t-1} + (dt*z)*B[t][n]; y = sum_n h*C + z*Dp.
// ---------------------------------------------------------------------------
__global__ __launch_bounds__(256) void ssm_scan(
    const float* __restrict__ dt, const float* __restrict__ z,
    const float* __restrict__ bc, const float* __restrict__ A_log,
    const float* __restrict__ Dp, unsigned short* __restrict__ ybf) {
  int gtid = blockIdx.x * 256 + threadIdx.x;
  int n = gtid & 15;
  int ch = gtid >> 4;          // 0..4095
  int b = ch >> 11, d = ch & 2047;
  float An = -__expf(A_log[d * 16 + n]);
  float Dd = Dp[d];
  const size_t tb = (size_t)b * 1024;
  const float* dtp = dt + tb * 2048 + d;
  const float* zp  = z  + tb * 2048 + d;
  const float* Bp  = bc + tb * 32 + n;
  const float* Cp  = Bp + 16;
  unsigned short* yp = ybf + tb * 2048 + d;

  float h = 0.0f;
  float cdt[4], cz[4], cB[4], cC[4];
#pragma unroll
  for (int u = 0; u < 4; ++u) {
    cdt[u] = dtp[(size_t)u * 2048];
    cz[u]  = zp[(size_t)u * 2048];
    cB[u]  = Bp[u * 32];
    cC[u]  = Cp[u * 32];
  }
  for (int t0 = 0; t0 < 1024; t0 += 4) {
    float ndt[4] = {}, nz[4] = {}, nB[4] = {}, nC[4] = {};
    if (t0 + 4 < 1024) {
#pragma unroll
      for (int u = 0; u < 4; ++u) {
        size_t t = (size_t)(t0 + 4 + u);
        ndt[u] = dtp[t * 2048];
        nz[u]  = zp[t * 2048];
        nB[u]  = Bp[t * 32];
        nC[u]  = Cp[t * 32];
      }
    }
#pragma unroll
    for (int u = 0; u < 4; ++u) {
      float dtv = cdt[u];
      float dA = __expf(dtv * An);
      h = __builtin_fmaf(dA, h, dtv * cz[u] * cB[u]);
      float contrib = h * cC[u];
      contrib += __shfl_xor(contrib, 1);
      contrib += __shfl_xor(contrib, 2);
      contrib += __shfl_xor(contrib, 4);
      contrib += __shfl_xor(contrib, 8);
      if (n == 0) yp[(size_t)(t0 + u) * 2048] = f2bf(contrib + cz[u] * Dd);
    }
#pragma unroll
    for (int u = 0; u < 4; ++u) { cdt[u] = ndt[u]; cz[u] = nz[u]; cB[u] = nB[u]; cC[u] = nC[u]; }
  }
}

// ---------------------------------------------------------------------------
// act = silu(g) * u from padded gu buffer [2048][5632] (g: 0..2815, u: 2816..).
// Valid cols 0..2751 only. Writes bf16 [2048][2752].
// ---------------------------------------------------------------------------
__global__ void actfuse(const float* __restrict__ gu, unsigned short* __restrict__ act) {
  int i = blockIdx.x * blockDim.x + threadIdx.x;  // over 2048*688 float4 groups
  int row = i / 688, c4 = i - row * 688;
  float4 g = *(const float4*)&gu[(size_t)row * 5632 + c4 * 4];
  float4 u = *(const float4*)&gu[(size_t)row * 5632 + 2816 + c4 * 4];
  ushort4 o;
  o.x = f2bf(g.x / (1.0f + __expf(-g.x)) * u.x);
  o.y = f2bf(g.y / (1.0f + __expf(-g.y)) * u.y);
  o.z = f2bf(g.z / (1.0f + __expf(-g.z)) * u.z);
  o.w = f2bf(g.w / (1.0f + __expf(-g.w)) * u.w);
  *(ushort4*)&act[(size_t)row * 2752 + c4 * 4] = o;
}

// ---------------------------------------------------------------------------
extern "C" void kernel_launch(void* const* d_in, const int* in_sizes, int n_in,
                              void* d_out, int out_size, void* d_ws, size_t ws_size,
                              hipStream_t stream) {
  const float* x         = (const float*)d_in[0];
  const float* norm1_w   = (const float*)d_in[1];
  const float* in_proj_w = (const float*)d_in[2];
  const float* gate_w    = (const float*)d_in[3];
  const float* dt_w      = (const float*)d_in[4];
  const float* dt_b      = (const float*)d_in[5];
  const float* x_proj_w  = (const float*)d_in[6];
  const float* A_log     = (const float*)d_in[7];
  const float* Dp        = (const float*)d_in[8];
  const float* out_w     = (const float*)d_in[9];
  const float* ffn_nw    = (const float*)d_in[10];
  const float* ffn_g     = (const float*)d_in[11];
  const float* ffn_u     = (const float*)d_in[12];
  const float* ffn_d     = (const float*)d_in[13];
  float* out = (float*)d_out;

  char* p = (char*)d_ws;
  auto alloc = [&](size_t b) { char* r = p; p += (b + 255) & ~(size_t)255; return r; };
  unsigned short* h_bf   = (unsigned short*)alloc(2048ull * 1024 * 2);
  float* big             = (float*)alloc(2048ull * 5632 * 4);  // zg then gu (disjoint lifetimes)
  float* z32             = (float*)alloc(2048ull * 2048 * 4);
  unsigned short* zbf    = (unsigned short*)alloc(2048ull * 2048 * 2);
  float* dt32            = (float*)alloc(2048ull * 2048 * 4);
  float* bc              = (float*)alloc(2048ull * 32 * 4);
  unsigned short* ybf    = (unsigned short*)alloc(2048ull * 2048 * 2);
  float* x2              = (float*)alloc(2048ull * 1024 * 4);
  unsigned short* hn_bf  = (unsigned short*)alloc(2048ull * 1024 * 2);
  unsigned short* act_bf = (unsigned short*)alloc(2048ull * 2752 * 2);
  unsigned short* w_in   = (unsigned short*)alloc(2048ull * 1024 * 2);
  unsigned short* w_gate = (unsigned short*)alloc(2048ull * 1024 * 2);
  unsigned short* w_dt   = (unsigned short*)alloc(2048ull * 2048 * 2);
  unsigned short* w_out  = (unsigned short*)alloc(1024ull * 2048 * 2);
  unsigned short* w_g    = (unsigned short*)alloc(2816ull * 1024 * 2);
  unsigned short* w_u    = (unsigned short*)alloc(2816ull * 1024 * 2);
  unsigned short* w_d    = (unsigned short*)alloc(1024ull * 2752 * 2);

  auto cvt = [&](const float* s, unsigned short* dst, int rows, int cols, int dst_rows) {
    int ng = dst_rows * (cols / 4);
    cvt_bf16<<<(ng + 255) / 256, 256, 0, stream>>>(s, dst, rows, cols / 4, dst_rows);
  };
  cvt(in_proj_w, w_in, 2048, 1024, 2048);
  cvt(gate_w,    w_gate, 2048, 1024, 2048);
  cvt(dt_w,      w_dt, 2048, 2048, 2048);
  cvt(out_w,     w_out, 1024, 2048, 1024);
  cvt(ffn_g,     w_g, 2752, 1024, 2816);   // pad rows 2752..2815 with zeros
  cvt(ffn_u,     w_u, 2752, 1024, 2816);
  cvt(ffn_d,     w_d, 1024, 2752, 1024);

  // 1) h = rmsnorm(x) -> bf16
  rmsnorm_bf16<<<2048, 256, 0, stream>>>(x, norm1_w, h_bf);
  // 2) zg = h @ [in_proj; gate_proj]^T  (N=4096)
  gemm_bt<0><<<dim3(32, 16), 256, 0, stream>>>(h_bf, w_in, w_gate, 16, 1024, big, 4096, nullptr);
  // 3) z = z * sigmoid(gate)
  zfuse<<<4096, 256, 0, stream>>>(big, z32, zbf);
  // 4) dt = softplus(z @ dt_w^T + dt_b)
  gemm_bt<1><<<dim3(16, 16), 256, 0, stream>>>(zbf, w_dt, w_dt, 16, 2048, dt32, 2048, dt_b);
  // 5) BC = z @ x_proj^T
  xproj<<<256, 256, 0, stream>>>(z32, x_proj_w, bc);
  // 6) selective scan -> y (bf16)
  ssm_scan<<<256, 256, 0, stream>>>(dt32, z32, bc, A_log, Dp, ybf);
  // 7) x2 = x + y @ out_proj^T
  gemm_bt<2><<<dim3(8, 16), 256, 0, stream>>>(ybf, w_out, w_out, 8, 2048, x2, 1024, x);
  // 8) hn = rmsnorm(x2) -> bf16
  rmsnorm_bf16<<<2048, 256, 0, stream>>>(x2, ffn_nw, hn_bf);
  // 9) gu = hn @ [ffn_gate; ffn_up]^T  (N=2*2816 padded)
  gemm_bt<0><<<dim3(44, 16), 256, 0, stream>>>(hn_bf, w_g, w_u, 22, 1024, big, 5632, nullptr);
  // 10) act = silu(g) * u -> bf16
  actfuse<<<5504, 256, 0, stream>>>(big, act_bf);
  // 11) out = x2 + act @ ffn_down^T
  gemm_bt<2><<<dim3(8, 16), 256, 0, stream>>>(act_bf, w_d, w_d, 8, 2752, out, 1024, x2);
}

// Round 2
// 542.670 us; speedup vs baseline: 1.4107x; 1.4107x over previous
//
#include <hip/hip_runtime.h>
#include <cstdint>
#include <cstddef>

// ---------------------------------------------------------------------------
// Mamba-style prelude block on MI355X (gfx950).
// Round 2: replaced latency-bound serial ssm_scan (303 us, 1 wave/SIMD,
// 4-deep shuffle chain per step) with a 3-phase chunked scan:
//   phase1: per-(b,d,chunk) lane, 16 n-states in registers -> (P,S) per chunk
//   phase2: combine across 32 chunks -> chunk-entry states H
//   phase3: recompute within chunk from H, fused y = sum_n h*C + z*Dp
// No cross-lane ops; exp2 native; B/C staged in LDS (broadcast reads).
// ---------------------------------------------------------------------------

#define BM 128
#define BN 128
#define BK 32

typedef __attribute__((ext_vector_type(8))) short short8;   // 8 bf16 (4 VGPRs)
typedef __attribute__((ext_vector_type(4))) float floatx4;  // 4 fp32 acc

__device__ __forceinline__ unsigned short f2bf(float f) {
  unsigned int u = __builtin_bit_cast(unsigned int, f);
  u = u + 0x7fffu + ((u >> 16) & 1u);   // round-to-nearest-even
  return (unsigned short)(u >> 16);
}

__device__ __forceinline__ void async_copy16(const unsigned short* g, unsigned short* l) {
  __builtin_amdgcn_global_load_lds(
      (__attribute__((address_space(1))) void*)(const_cast<unsigned short*>(g)),
      (__attribute__((address_space(3))) void*)(l), 16, 0, 0);
}

// ---------------------------------------------------------------------------
// fp32 -> bf16 weight conversion with optional row padding (zeros).
// ---------------------------------------------------------------------------
__global__ void cvt_bf16(const float* __restrict__ src, unsigned short* __restrict__ dst,
                         int rows, int cols4, int dst_rows) {
  int i = blockIdx.x * blockDim.x + threadIdx.x;
  int total = dst_rows * cols4;
  if (i >= total) return;
  int r = i / cols4, c = i - r * cols4;
  ushort4 o = {0, 0, 0, 0};
  if (r < rows) {
    float4 v = *(const float4*)&src[((size_t)r * cols4 + c) * 4];
    o.x = f2bf(v.x); o.y = f2bf(v.y); o.z = f2bf(v.z); o.w = f2bf(v.w);
  }
  *(ushort4*)&dst[((size_t)r * cols4 + c) * 4] = o;
}

// ---------------------------------------------------------------------------
// RMSNorm: one block (256 thr) per row of D=1024 fp32, writes bf16.
// ---------------------------------------------------------------------------
__global__ __launch_bounds__(256) void rmsnorm_bf16(
    const float* __restrict__ x, const float* __restrict__ w,
    unsigned short* __restrict__ out) {
  const int D = 1024;
  int row = blockIdx.x;
  int t = threadIdx.x;
  const float* xr = x + (size_t)row * D;
  float4 v = *(const float4*)&xr[t * 4];
  float ss = v.x * v.x + v.y * v.y + v.z * v.z + v.w * v.w;
#pragma unroll
  for (int m = 1; m < 64; m <<= 1) ss += __shfl_xor(ss, m);
  __shared__ float ws_[4];
  if ((t & 63) == 0) ws_[t >> 6] = ss;
  __syncthreads();
  float tot = ws_[0] + ws_[1] + ws_[2] + ws_[3];
  float scale = rsqrtf(tot * (1.0f / D) + 1e-6f);
  ushort4 o;
  o.x = f2bf(v.x * scale * w[t * 4 + 0]);
  o.y = f2bf(v.y * scale * w[t * 4 + 1]);
  o.z = f2bf(v.z * scale * w[t * 4 + 2]);
  o.w = f2bf(v.w * scale * w[t * 4 + 3]);
  *(ushort4*)&out[(size_t)row * D + t * 4] = o;
}

// ---------------------------------------------------------------------------
// bf16 MFMA GEMM, C = A @ W^T. 128x128 tile, BK=32, m97 pattern.
// EPI: 0 = plain store, 1 = softplus(acc + bias[col]), 2 = acc + res[row][col].
// ---------------------------------------------------------------------------
template <int EPI>
__global__ __launch_bounds__(256, 2) void gemm_bt(
    const unsigned short* __restrict__ A,
    const unsigned short* __restrict__ W1,
    const unsigned short* __restrict__ W2,
    int n1_blocks, int K,
    float* __restrict__ C, int ldc,
    const float* __restrict__ aux) {
  __shared__ __align__(16) unsigned short As[BM * BK];
  __shared__ __align__(16) unsigned short Bs[BN * BK];
  const int tid = threadIdx.x;
  const int wave = tid >> 6, lane = tid & 63;
  const int bn = blockIdx.x, bm = blockIdx.y;
  const unsigned short* W;
  int wrow0;
  if (bn < n1_blocks) { W = W1; wrow0 = bn * BN; }
  else                { W = W2; wrow0 = (bn - n1_blocks) * BN; }
  const int m0 = bm * BM;
  const int wm = wave >> 1, wn = wave & 1;
  const int l15 = lane & 15, quad = lane >> 4;

  floatx4 acc[4][4] = {};

  const int c0 = wave * 64 + lane;
  const int r0 = c0 >> 2, k0off = (c0 & 3) * 8;
  const int c1 = c0 + 256;
  const int r1 = c1 >> 2, k1off = (c1 & 3) * 8;

  const int nk = K / BK;
  for (int kt = 0; kt < nk; ++kt) {
    __syncthreads();
    const int kb = kt * BK;
    async_copy16(A + (size_t)(m0 + r0) * K + kb + k0off, &As[c0 * 8]);
    async_copy16(A + (size_t)(m0 + r1) * K + kb + k1off, &As[c1 * 8]);
    async_copy16(W + (size_t)(wrow0 + r0) * K + kb + k0off, &Bs[c0 * 8]);
    async_copy16(W + (size_t)(wrow0 + r1) * K + kb + k1off, &Bs[c1 * 8]);
    __syncthreads();

    short8 af[4], bf[4];
#pragma unroll
    for (int i = 0; i < 4; ++i)
      af[i] = *(const short8*)&As[(wm * 64 + i * 16 + l15) * BK + quad * 8];
#pragma unroll
    for (int j = 0; j < 4; ++j)
      bf[j] = *(const short8*)&Bs[(wn * 64 + j * 16 + l15) * BK + quad * 8];
#pragma unroll
    for (int i = 0; i < 4; ++i)
#pragma unroll
      for (int j = 0; j < 4; ++j)
        acc[i][j] = __builtin_amdgcn_mfma_f32_16x16x32_bf16(af[i], bf[j], acc[i][j], 0, 0, 0);
  }

#pragma unroll
  for (int i = 0; i < 4; ++i)
#pragma unroll
    for (int j = 0; j < 4; ++j)
#pragma unroll
      for (int r = 0; r < 4; ++r) {
        int gr = m0 + wm * 64 + i * 16 + quad * 4 + r;
        int gc = bn * BN + wn * 64 + j * 16 + l15;
        float v = acc[i][j][r];
        if (EPI == 1) {
          v += aux[gc];
          v = fmaxf(v, 0.0f) + log1pf(__expf(-fabsf(v)));
        } else if (EPI == 2) {
          v += aux[(size_t)gr * ldc + gc];
        }
        C[(size_t)gr * ldc + gc] = v;
      }
}

// ---------------------------------------------------------------------------
// z = z_raw * sigmoid(gate_raw); writes fp32 (for scan) + bf16 (for dt GEMM).
// ---------------------------------------------------------------------------
__global__ void zfuse(const float* __restrict__ zg, float* __restrict__ z32,
                      unsigned short* __restrict__ zbf) {
  int i = blockIdx.x * blockDim.x + threadIdx.x;
  int row = i >> 9, c4 = i & 511;
  float4 zr = *(const float4*)&zg[(size_t)row * 4096 + c4 * 4];
  float4 gr = *(const float4*)&zg[(size_t)row * 4096 + 2048 + c4 * 4];
  float4 o;
  o.x = zr.x / (1.0f + __expf(-gr.x));
  o.y = zr.y / (1.0f + __expf(-gr.y));
  o.z = zr.z / (1.0f + __expf(-gr.z));
  o.w = zr.w / (1.0f + __expf(-gr.w));
  *(float4*)&z32[(size_t)row * 2048 + c4 * 4] = o;
  ushort4 ob;
  ob.x = f2bf(o.x); ob.y = f2bf(o.y); ob.z = f2bf(o.z); ob.w = f2bf(o.w);
  *(ushort4*)&zbf[(size_t)row * 2048 + c4 * 4] = ob;
}

// ---------------------------------------------------------------------------
// BC = z @ x_proj^T  (M=2048, N=32, K=2048, fp32).
// ---------------------------------------------------------------------------
__global__ __launch_bounds__(256) void xproj(const float* __restrict__ z,
                                             const float* __restrict__ xw,
                                             float* __restrict__ bc) {
  int r = threadIdx.x >> 5, n = threadIdx.x & 31;
  int row = blockIdx.x * 8 + r;
  const float4* zp = (const float4*)(z + (size_t)row * 2048);
  const float4* wp = (const float4*)(xw + (size_t)n * 2048);
  float acc = 0.0f;
#pragma unroll 4
  for (int k = 0; k < 512; ++k) {
    float4 a = zp[k], b = wp[k];
    acc += a.x * b.x + a.y * b.y + a.z * b.z + a.w * b.w;
  }
  bc[(size_t)row * 32 + n] = acc;
}

// ---------------------------------------------------------------------------
// Chunked selective scan. T=1024 = 32 chunks x 32 steps.
// Recurrence per (b,d,n): h_t = exp(dt*A) * h_{t-1} + (dt*z)*B_t
// Phase 1: lane = (b, d, chunk); 16 n-states in regs; emit P=prod(dA),
//          S=chunk-local scan end. Layout [(c*2+b)*2048+d]*16+n.
// ---------------------------------------------------------------------------
__global__ __launch_bounds__(256) void scan_phase1(
    const float* __restrict__ dt, const float* __restrict__ z,
    const float* __restrict__ bc, const float* __restrict__ A_log,
    float* __restrict__ P, float* __restrict__ S) {
  const int d = blockIdx.x * 256 + threadIdx.x;
  const int c = blockIdx.y, b = blockIdx.z;
  __shared__ float bcs[1024];  // 32 t x (16 B | 16 C)
  const float* src = bc + ((size_t)b * 1024 + c * 32) * 32;
  ((float4*)bcs)[threadIdx.x] = ((const float4*)src)[threadIdx.x];
  __syncthreads();
  float A2[16];
#pragma unroll
  for (int n = 0; n < 16; ++n) A2[n] = -__expf(A_log[d * 16 + n]) * 1.44269504f;
  float p[16], s[16];
#pragma unroll
  for (int n = 0; n < 16; ++n) { p[n] = 1.0f; s[n] = 0.0f; }
  const size_t base = ((size_t)b * 1024 + c * 32) * 2048 + d;
#pragma unroll 4
  for (int t = 0; t < 32; ++t) {
    float dtv = dt[base + (size_t)t * 2048];
    float zv  = z [base + (size_t)t * 2048];
    float dtz = dtv * zv;
#pragma unroll
    for (int n = 0; n < 16; ++n) {
      float dA = exp2f(dtv * A2[n]);
      s[n] = __builtin_fmaf(dA, s[n], dtz * bcs[t * 32 + n]);
      p[n] *= dA;
    }
  }
  float* Pp = P + (((size_t)c * 2 + b) * 2048 + d) * 16;
  float* Sp = S + (((size_t)c * 2 + b) * 2048 + d) * 16;
#pragma unroll
  for (int n = 0; n < 16; ++n) { Pp[n] = p[n]; Sp[n] = s[n]; }
}

// Phase 2: per (b,d,n) combine across chunks; H[c] = state entering chunk c.
__global__ __launch_bounds__(256) void scan_phase2(
    const float* __restrict__ P, const float* __restrict__ S,
    float* __restrict__ H) {
  int i = blockIdx.x * 256 + threadIdx.x;  // i = (b*2048+d)*16+n
  float h = 0.0f;
#pragma unroll
  for (int c = 0; c < 32; ++c) {
    size_t idx = (size_t)c * 65536 + i;
    H[idx] = h;
    h = __builtin_fmaf(P[idx], h, S[idx]);
  }
}

// Phase 3: recompute within chunk from H; y = sum_n h*C + z*Dp -> bf16.
__global__ __launch_bounds__(256) void scan_phase3(
    const float* __restrict__ dt, const float* __restrict__ z,
    const float* __restrict__ bc, const float* __restrict__ A_log,
    const float* __restrict__ Dp, const float* __restrict__ H,
    unsigned short* __restrict__ ybf) {
  const int d = blockIdx.x * 256 + threadIdx.x;
  const int c = blockIdx.y, b = blockIdx.z;
  __shared__ float bcs[1024];
  const float* src = bc + ((size_t)b * 1024 + c * 32) * 32;
  ((float4*)bcs)[threadIdx.x] = ((const float4*)src)[threadIdx.x];
  __syncthreads();
  float A2[16];
#pragma unroll
  for (int n = 0; n < 16; ++n) A2[n] = -__expf(A_log[d * 16 + n]) * 1.44269504f;
  float h[16];
  const float* Hp = H + (((size_t)c * 2 + b) * 2048 + d) * 16;
#pragma unroll
  for (int n = 0; n < 16; ++n) h[n] = Hp[n];
  const float Dd = Dp[d];
  const size_t base = ((size_t)b * 1024 + c * 32) * 2048 + d;
#pragma unroll 4
  for (int t = 0; t < 32; ++t) {
    float dtv = dt[base + (size_t)t * 2048];
    float zv  = z [base + (size_t)t * 2048];
    float dtz = dtv * zv;
    float y = zv * Dd;
#pragma unroll
    for (int n = 0; n < 16; ++n) {
      float dA = exp2f(dtv * A2[n]);
      h[n] = __builtin_fmaf(dA, h[n], dtz * bcs[t * 32 + n]);
      y = __builtin_fmaf(h[n], bcs[t * 32 + 16 + n], y);
    }
    ybf[base + (size_t)t * 2048] = f2bf(y);
  }
}

// ---------------------------------------------------------------------------
// act = silu(g) * u from padded gu buffer [2048][5632].
// ---------------------------------------------------------------------------
__global__ void actfuse(const float* __restrict__ gu, unsigned short* __restrict__ act) {
  int i = blockIdx.x * blockDim.x + threadIdx.x;
  int row = i / 688, c4 = i - row * 688;
  float4 g = *(const float4*)&gu[(size_t)row * 5632 + c4 * 4];
  float4 u = *(const float4*)&gu[(size_t)row * 5632 + 2816 + c4 * 4];
  ushort4 o;
  o.x = f2bf(g.x / (1.0f + __expf(-g.x)) * u.x);
  o.y = f2bf(g.y / (1.0f + __expf(-g.y)) * u.y);
  o.z = f2bf(g.z / (1.0f + __expf(-g.z)) * u.z);
  o.w = f2bf(g.w / (1.0f + __expf(-g.w)) * u.w);
  *(ushort4*)&act[(size_t)row * 2752 + c4 * 4] = o;
}

// ---------------------------------------------------------------------------
extern "C" void kernel_launch(void* const* d_in, const int* in_sizes, int n_in,
                              void* d_out, int out_size, void* d_ws, size_t ws_size,
                              hipStream_t stream) {
  const float* x         = (const float*)d_in[0];
  const float* norm1_w   = (const float*)d_in[1];
  const float* in_proj_w = (const float*)d_in[2];
  const float* gate_w    = (const float*)d_in[3];
  const float* dt_w      = (const float*)d_in[4];
  const float* dt_b      = (const float*)d_in[5];
  const float* x_proj_w  = (const float*)d_in[6];
  const float* A_log     = (const float*)d_in[7];
  const float* Dp        = (const float*)d_in[8];
  const float* out_w     = (const float*)d_in[9];
  const float* ffn_nw    = (const float*)d_in[10];
  const float* ffn_g     = (const float*)d_in[11];
  const float* ffn_u     = (const float*)d_in[12];
  const float* ffn_d     = (const float*)d_in[13];
  float* out = (float*)d_out;

  char* p = (char*)d_ws;
  auto alloc = [&](size_t b) { char* r = p; p += (b + 255) & ~(size_t)255; return r; };
  unsigned short* h_bf   = (unsigned short*)alloc(2048ull * 1024 * 2);
  float* big             = (float*)alloc(2048ull * 5632 * 4);  // zg | (P,S,H) | gu
  float* z32             = (float*)alloc(2048ull * 2048 * 4);
  unsigned short* zbf    = (unsigned short*)alloc(2048ull * 2048 * 2);
  float* dt32            = (float*)alloc(2048ull * 2048 * 4);
  float* bc              = (float*)alloc(2048ull * 32 * 4);
  unsigned short* ybf    = (unsigned short*)alloc(2048ull * 2048 * 2);
  float* x2              = (float*)alloc(2048ull * 1024 * 4);
  unsigned short* hn_bf  = (unsigned short*)alloc(2048ull * 1024 * 2);
  unsigned short* act_bf = (unsigned short*)alloc(2048ull * 2752 * 2);
  unsigned short* w_in   = (unsigned short*)alloc(2048ull * 1024 * 2);
  unsigned short* w_gate = (unsigned short*)alloc(2048ull * 1024 * 2);
  unsigned short* w_dt   = (unsigned short*)alloc(2048ull * 2048 * 2);
  unsigned short* w_out  = (unsigned short*)alloc(1024ull * 2048 * 2);
  unsigned short* w_g    = (unsigned short*)alloc(2816ull * 1024 * 2);
  unsigned short* w_u    = (unsigned short*)alloc(2816ull * 1024 * 2);
  unsigned short* w_d    = (unsigned short*)alloc(1024ull * 2752 * 2);

  // Chunk-scan state reuses `big` (zg dead after zfuse, gu not live yet).
  float* Pb = big;                       // 32*2*2048*16 = 2M floats
  float* Sb = big + 2097152;
  float* Hb = big + 4194304;

  auto cvt = [&](const float* s, unsigned short* dst, int rows, int cols, int dst_rows) {
    int ng = dst_rows * (cols / 4);
    cvt_bf16<<<(ng + 255) / 256, 256, 0, stream>>>(s, dst, rows, cols / 4, dst_rows);
  };
  cvt(in_proj_w, w_in, 2048, 1024, 2048);
  cvt(gate_w,    w_gate, 2048, 1024, 2048);
  cvt(dt_w,      w_dt, 2048, 2048, 2048);
  cvt(out_w,     w_out, 1024, 2048, 1024);
  cvt(ffn_g,     w_g, 2752, 1024, 2816);
  cvt(ffn_u,     w_u, 2752, 1024, 2816);
  cvt(ffn_d,     w_d, 1024, 2752, 1024);

  // 1) h = rmsnorm(x) -> bf16
  rmsnorm_bf16<<<2048, 256, 0, stream>>>(x, norm1_w, h_bf);
  // 2) zg = h @ [in_proj; gate_proj]^T  (N=4096)
  gemm_bt<0><<<dim3(32, 16), 256, 0, stream>>>(h_bf, w_in, w_gate, 16, 1024, big, 4096, nullptr);
  // 3) z = z * sigmoid(gate)
  zfuse<<<4096, 256, 0, stream>>>(big, z32, zbf);
  // 4) dt = softplus(z @ dt_w^T + dt_b)
  gemm_bt<1><<<dim3(16, 16), 256, 0, stream>>>(zbf, w_dt, w_dt, 16, 2048, dt32, 2048, dt_b);
  // 5) BC = z @ x_proj^T
  xproj<<<256, 256, 0, stream>>>(z32, x_proj_w, bc);
  // 6) chunked selective scan -> y (bf16)
  scan_phase1<<<dim3(8, 32, 2), 256, 0, stream>>>(dt32, z32, bc, A_log, Pb, Sb);
  scan_phase2<<<256, 256, 0, stream>>>(Pb, Sb, Hb);
  scan_phase3<<<dim3(8, 32, 2), 256, 0, stream>>>(dt32, z32, bc, A_log, Dp, Hb, ybf);
  // 7) x2 = x + y @ out_proj^T
  gemm_bt<2><<<dim3(8, 16), 256, 0, stream>>>(ybf, w_out, w_out, 8, 2048, x2, 1024, x);
  // 8) hn = rmsnorm(x2) -> bf16
  rmsnorm_bf16<<<2048, 256, 0, stream>>>(x2, ffn_nw, hn_bf);
  // 9) gu = hn @ [ffn_gate; ffn_up]^T  (N=2*2816 padded)
  gemm_bt<0><<<dim3(44, 16), 256, 0, stream>>>(hn_bf, w_g, w_u, 22, 1024, big, 5632, nullptr);
  // 10) act = silu(g) * u -> bf16
  actfuse<<<5504, 256, 0, stream>>>(big, act_bf);
  // 11) out = x2 + act @ ffn_down^T
  gemm_bt<2><<<dim3(8, 16), 256, 0, stream>>>(act_bf, w_d, w_d, 8, 2752, out, 1024, x2);
}

// Round 3
// 542.364 us; speedup vs baseline: 1.4115x; 1.0006x over previous
//
#include <hip/hip_runtime.h>
#include <cstdint>
#include <cstddef>

// ---------------------------------------------------------------------------
// Mamba-style prelude block on MI355X (gfx950).
// Round 3: xproj was latency-bound (83 us, 1 wave/SIMD, 512 serial loads per
// thread). Rewritten: 1024 blocks (2 rows each), K split 4-way per thread
// (128 float4 iters) + LDS cross-slice reduction -> 16 waves/CU.
// ---------------------------------------------------------------------------

#define BM 128
#define BN 128
#define BK 32

typedef __attribute__((ext_vector_type(8))) short short8;   // 8 bf16 (4 VGPRs)
typedef __attribute__((ext_vector_type(4))) float floatx4;  // 4 fp32 acc

__device__ __forceinline__ unsigned short f2bf(float f) {
  unsigned int u = __builtin_bit_cast(unsigned int, f);
  u = u + 0x7fffu + ((u >> 16) & 1u);   // round-to-nearest-even
  return (unsigned short)(u >> 16);
}

__device__ __forceinline__ void async_copy16(const unsigned short* g, unsigned short* l) {
  __builtin_amdgcn_global_load_lds(
      (__attribute__((address_space(1))) void*)(const_cast<unsigned short*>(g)),
      (__attribute__((address_space(3))) void*)(l), 16, 0, 0);
}

// ---------------------------------------------------------------------------
// fp32 -> bf16 weight conversion with optional row padding (zeros).
// ---------------------------------------------------------------------------
__global__ void cvt_bf16(const float* __restrict__ src, unsigned short* __restrict__ dst,
                         int rows, int cols4, int dst_rows) {
  int i = blockIdx.x * blockDim.x + threadIdx.x;
  int total = dst_rows * cols4;
  if (i >= total) return;
  int r = i / cols4, c = i - r * cols4;
  ushort4 o = {0, 0, 0, 0};
  if (r < rows) {
    float4 v = *(const float4*)&src[((size_t)r * cols4 + c) * 4];
    o.x = f2bf(v.x); o.y = f2bf(v.y); o.z = f2bf(v.z); o.w = f2bf(v.w);
  }
  *(ushort4*)&dst[((size_t)r * cols4 + c) * 4] = o;
}

// ---------------------------------------------------------------------------
// RMSNorm: one block (256 thr) per row of D=1024 fp32, writes bf16.
// ---------------------------------------------------------------------------
__global__ __launch_bounds__(256) void rmsnorm_bf16(
    const float* __restrict__ x, const float* __restrict__ w,
    unsigned short* __restrict__ out) {
  const int D = 1024;
  int row = blockIdx.x;
  int t = threadIdx.x;
  const float* xr = x + (size_t)row * D;
  float4 v = *(const float4*)&xr[t * 4];
  float ss = v.x * v.x + v.y * v.y + v.z * v.z + v.w * v.w;
#pragma unroll
  for (int m = 1; m < 64; m <<= 1) ss += __shfl_xor(ss, m);
  __shared__ float ws_[4];
  if ((t & 63) == 0) ws_[t >> 6] = ss;
  __syncthreads();
  float tot = ws_[0] + ws_[1] + ws_[2] + ws_[3];
  float scale = rsqrtf(tot * (1.0f / D) + 1e-6f);
  ushort4 o;
  o.x = f2bf(v.x * scale * w[t * 4 + 0]);
  o.y = f2bf(v.y * scale * w[t * 4 + 1]);
  o.z = f2bf(v.z * scale * w[t * 4 + 2]);
  o.w = f2bf(v.w * scale * w[t * 4 + 3]);
  *(ushort4*)&out[(size_t)row * D + t * 4] = o;
}

// ---------------------------------------------------------------------------
// bf16 MFMA GEMM, C = A @ W^T. 128x128 tile, BK=32, m97 pattern.
// EPI: 0 = plain store, 1 = softplus(acc + bias[col]), 2 = acc + res[row][col].
// ---------------------------------------------------------------------------
template <int EPI>
__global__ __launch_bounds__(256, 2) void gemm_bt(
    const unsigned short* __restrict__ A,
    const unsigned short* __restrict__ W1,
    const unsigned short* __restrict__ W2,
    int n1_blocks, int K,
    float* __restrict__ C, int ldc,
    const float* __restrict__ aux) {
  __shared__ __align__(16) unsigned short As[BM * BK];
  __shared__ __align__(16) unsigned short Bs[BN * BK];
  const int tid = threadIdx.x;
  const int wave = tid >> 6, lane = tid & 63;
  const int bn = blockIdx.x, bm = blockIdx.y;
  const unsigned short* W;
  int wrow0;
  if (bn < n1_blocks) { W = W1; wrow0 = bn * BN; }
  else                { W = W2; wrow0 = (bn - n1_blocks) * BN; }
  const int m0 = bm * BM;
  const int wm = wave >> 1, wn = wave & 1;
  const int l15 = lane & 15, quad = lane >> 4;

  floatx4 acc[4][4] = {};

  const int c0 = wave * 64 + lane;
  const int r0 = c0 >> 2, k0off = (c0 & 3) * 8;
  const int c1 = c0 + 256;
  const int r1 = c1 >> 2, k1off = (c1 & 3) * 8;

  const int nk = K / BK;
  for (int kt = 0; kt < nk; ++kt) {
    __syncthreads();
    const int kb = kt * BK;
    async_copy16(A + (size_t)(m0 + r0) * K + kb + k0off, &As[c0 * 8]);
    async_copy16(A + (size_t)(m0 + r1) * K + kb + k1off, &As[c1 * 8]);
    async_copy16(W + (size_t)(wrow0 + r0) * K + kb + k0off, &Bs[c0 * 8]);
    async_copy16(W + (size_t)(wrow0 + r1) * K + kb + k1off, &Bs[c1 * 8]);
    __syncthreads();

    short8 af[4], bf[4];
#pragma unroll
    for (int i = 0; i < 4; ++i)
      af[i] = *(const short8*)&As[(wm * 64 + i * 16 + l15) * BK + quad * 8];
#pragma unroll
    for (int j = 0; j < 4; ++j)
      bf[j] = *(const short8*)&Bs[(wn * 64 + j * 16 + l15) * BK + quad * 8];
#pragma unroll
    for (int i = 0; i < 4; ++i)
#pragma unroll
      for (int j = 0; j < 4; ++j)
        acc[i][j] = __builtin_amdgcn_mfma_f32_16x16x32_bf16(af[i], bf[j], acc[i][j], 0, 0, 0);
  }

#pragma unroll
  for (int i = 0; i < 4; ++i)
#pragma unroll
    for (int j = 0; j < 4; ++j)
#pragma unroll
      for (int r = 0; r < 4; ++r) {
        int gr = m0 + wm * 64 + i * 16 + quad * 4 + r;
        int gc = bn * BN + wn * 64 + j * 16 + l15;
        float v = acc[i][j][r];
        if (EPI == 1) {
          v += aux[gc];
          v = fmaxf(v, 0.0f) + log1pf(__expf(-fabsf(v)));
        } else if (EPI == 2) {
          v += aux[(size_t)gr * ldc + gc];
        }
        C[(size_t)gr * ldc + gc] = v;
      }
}

// ---------------------------------------------------------------------------
// z = z_raw * sigmoid(gate_raw); writes fp32 (for scan) + bf16 (for dt GEMM).
// ---------------------------------------------------------------------------
__global__ void zfuse(const float* __restrict__ zg, float* __restrict__ z32,
                      unsigned short* __restrict__ zbf) {
  int i = blockIdx.x * blockDim.x + threadIdx.x;
  int row = i >> 9, c4 = i & 511;
  float4 zr = *(const float4*)&zg[(size_t)row * 4096 + c4 * 4];
  float4 gr = *(const float4*)&zg[(size_t)row * 4096 + 2048 + c4 * 4];
  float4 o;
  o.x = zr.x / (1.0f + __expf(-gr.x));
  o.y = zr.y / (1.0f + __expf(-gr.y));
  o.z = zr.z / (1.0f + __expf(-gr.z));
  o.w = zr.w / (1.0f + __expf(-gr.w));
  *(float4*)&z32[(size_t)row * 2048 + c4 * 4] = o;
  ushort4 ob;
  ob.x = f2bf(o.x); ob.y = f2bf(o.y); ob.z = f2bf(o.z); ob.w = f2bf(o.w);
  *(ushort4*)&zbf[(size_t)row * 2048 + c4 * 4] = ob;
}

// ---------------------------------------------------------------------------
// BC = z @ x_proj^T  (M=2048, N=32, K=2048, fp32).
// Round 3: 1024 blocks x 2 rows; thread = (r, n, ks): ks-th 512-slice of K.
// LDS reduce across the 4 k-slices. 16 waves/CU; weight is L2-resident.
// ---------------------------------------------------------------------------
__global__ __launch_bounds__(256) void xproj(const float* __restrict__ z,
                                             const float* __restrict__ xw,
                                             float* __restrict__ bc) {
  const int t = threadIdx.x;
  const int n = t & 31, ks = (t >> 5) & 3, r = t >> 7;
  const int row = blockIdx.x * 2 + r;
  const float4* zp = (const float4*)(z + (size_t)row * 2048) + ks * 128;
  const float4* wp = (const float4*)(xw + (size_t)n * 2048) + ks * 128;
  float acc = 0.0f;
#pragma unroll 8
  for (int k = 0; k < 128; ++k) {
    float4 a = zp[k], b = wp[k];
    acc += a.x * b.x + a.y * b.y + a.z * b.z + a.w * b.w;
  }
  __shared__ float red[256];
  red[t] = acc;
  __syncthreads();
  if (t < 64) {
    int rr = t >> 5, nn = t & 31;
    float s = red[rr * 128 + nn] + red[rr * 128 + 32 + nn] +
              red[rr * 128 + 64 + nn] + red[rr * 128 + 96 + nn];
    bc[(size_t)(blockIdx.x * 2 + rr) * 32 + nn] = s;
  }
}

// ---------------------------------------------------------------------------
// Chunked selective scan. T=1024 = 32 chunks x 32 steps.
// ---------------------------------------------------------------------------
__global__ __launch_bounds__(256) void scan_phase1(
    const float* __restrict__ dt, const float* __restrict__ z,
    const float* __restrict__ bc, const float* __restrict__ A_log,
    float* __restrict__ P, float* __restrict__ S) {
  const int d = blockIdx.x * 256 + threadIdx.x;
  const int c = blockIdx.y, b = blockIdx.z;
  __shared__ float bcs[1024];  // 32 t x (16 B | 16 C)
  const float* src = bc + ((size_t)b * 1024 + c * 32) * 32;
  ((float4*)bcs)[threadIdx.x] = ((const float4*)src)[threadIdx.x];
  __syncthreads();
  float A2[16];
#pragma unroll
  for (int n = 0; n < 16; ++n) A2[n] = -__expf(A_log[d * 16 + n]) * 1.44269504f;
  float p[16], s[16];
#pragma unroll
  for (int n = 0; n < 16; ++n) { p[n] = 1.0f; s[n] = 0.0f; }
  const size_t base = ((size_t)b * 1024 + c * 32) * 2048 + d;
#pragma unroll 4
  for (int t = 0; t < 32; ++t) {
    float dtv = dt[base + (size_t)t * 2048];
    float zv  = z [base + (size_t)t * 2048];
    float dtz = dtv * zv;
#pragma unroll
    for (int n = 0; n < 16; ++n) {
      float dA = exp2f(dtv * A2[n]);
      s[n] = __builtin_fmaf(dA, s[n], dtz * bcs[t * 32 + n]);
      p[n] *= dA;
    }
  }
  float* Pp = P + (((size_t)c * 2 + b) * 2048 + d) * 16;
  float* Sp = S + (((size_t)c * 2 + b) * 2048 + d) * 16;
#pragma unroll
  for (int n = 0; n < 16; ++n) { Pp[n] = p[n]; Sp[n] = s[n]; }
}

// Phase 2: per (b,d,n) combine across chunks; H[c] = state entering chunk c.
__global__ __launch_bounds__(256) void scan_phase2(
    const float* __restrict__ P, const float* __restrict__ S,
    float* __restrict__ H) {
  int i = blockIdx.x * 256 + threadIdx.x;  // i = (b*2048+d)*16+n
  float h = 0.0f;
#pragma unroll
  for (int c = 0; c < 32; ++c) {
    size_t idx = (size_t)c * 65536 + i;
    H[idx] = h;
    h = __builtin_fmaf(P[idx], h, S[idx]);
  }
}

// Phase 3: recompute within chunk from H; y = sum_n h*C + z*Dp -> bf16.
__global__ __launch_bounds__(256) void scan_phase3(
    const float* __restrict__ dt, const float* __restrict__ z,
    const float* __restrict__ bc, const float* __restrict__ A_log,
    const float* __restrict__ Dp, const float* __restrict__ H,
    unsigned short* __restrict__ ybf) {
  const int d = blockIdx.x * 256 + threadIdx.x;
  const int c = blockIdx.y, b = blockIdx.z;
  __shared__ float bcs[1024];
  const float* src = bc + ((size_t)b * 1024 + c * 32) * 32;
  ((float4*)bcs)[threadIdx.x] = ((const float4*)src)[threadIdx.x];
  __syncthreads();
  float A2[16];
#pragma unroll
  for (int n = 0; n < 16; ++n) A2[n] = -__expf(A_log[d * 16 + n]) * 1.44269504f;
  float h[16];
  const float* Hp = H + (((size_t)c * 2 + b) * 2048 + d) * 16;
#pragma unroll
  for (int n = 0; n < 16; ++n) h[n] = Hp[n];
  const float Dd = Dp[d];
  const size_t base = ((size_t)b * 1024 + c * 32) * 2048 + d;
#pragma unroll 4
  for (int t = 0; t < 32; ++t) {
    float dtv = dt[base + (size_t)t * 2048];
    float zv  = z [base + (size_t)t * 2048];
    float dtz = dtv * zv;
    float y = zv * Dd;
#pragma unroll
    for (int n = 0; n < 16; ++n) {
      float dA = exp2f(dtv * A2[n]);
      h[n] = __builtin_fmaf(dA, h[n], dtz * bcs[t * 32 + n]);
      y = __builtin_fmaf(h[n], bcs[t * 32 + 16 + n], y);
    }
    ybf[base + (size_t)t * 2048] = f2bf(y);
  }
}

// ---------------------------------------------------------------------------
// act = silu(g) * u from padded gu buffer [2048][5632].
// ---------------------------------------------------------------------------
__global__ void actfuse(const float* __restrict__ gu, unsigned short* __restrict__ act) {
  int i = blockIdx.x * blockDim.x + threadIdx.x;
  int row = i / 688, c4 = i - row * 688;
  float4 g = *(const float4*)&gu[(size_t)row * 5632 + c4 * 4];
  float4 u = *(const float4*)&gu[(size_t)row * 5632 + 2816 + c4 * 4];
  ushort4 o;
  o.x = f2bf(g.x / (1.0f + __expf(-g.x)) * u.x);
  o.y = f2bf(g.y / (1.0f + __expf(-g.y)) * u.y);
  o.z = f2bf(g.z / (1.0f + __expf(-g.z)) * u.z);
  o.w = f2bf(g.w / (1.0f + __expf(-g.w)) * u.w);
  *(ushort4*)&act[(size_t)row * 2752 + c4 * 4] = o;
}

// ---------------------------------------------------------------------------
extern "C" void kernel_launch(void* const* d_in, const int* in_sizes, int n_in,
                              void* d_out, int out_size, void* d_ws, size_t ws_size,
                              hipStream_t stream) {
  const float* x         = (const float*)d_in[0];
  const float* norm1_w   = (const float*)d_in[1];
  const float* in_proj_w = (const float*)d_in[2];
  const float* gate_w    = (const float*)d_in[3];
  const float* dt_w      = (const float*)d_in[4];
  const float* dt_b      = (const float*)d_in[5];
  const float* x_proj_w  = (const float*)d_in[6];
  const float* A_log     = (const float*)d_in[7];
  const float* Dp        = (const float*)d_in[8];
  const float* out_w     = (const float*)d_in[9];
  const float* ffn_nw    = (const float*)d_in[10];
  const float* ffn_g     = (const float*)d_in[11];
  const float* ffn_u     = (const float*)d_in[12];
  const float* ffn_d     = (const float*)d_in[13];
  float* out = (float*)d_out;

  char* p = (char*)d_ws;
  auto alloc = [&](size_t b) { char* r = p; p += (b + 255) & ~(size_t)255; return r; };
  unsigned short* h_bf   = (unsigned short*)alloc(2048ull * 1024 * 2);
  float* big             = (float*)alloc(2048ull * 5632 * 4);  // zg | (P,S,H) | gu
  float* z32             = (float*)alloc(2048ull * 2048 * 4);
  unsigned short* zbf    = (unsigned short*)alloc(2048ull * 2048 * 2);
  float* dt32            = (float*)alloc(2048ull * 2048 * 4);
  float* bc              = (float*)alloc(2048ull * 32 * 4);
  unsigned short* ybf    = (unsigned short*)alloc(2048ull * 2048 * 2);
  float* x2              = (float*)alloc(2048ull * 1024 * 4);
  unsigned short* hn_bf  = (unsigned short*)alloc(2048ull * 1024 * 2);
  unsigned short* act_bf = (unsigned short*)alloc(2048ull * 2752 * 2);
  unsigned short* w_in   = (unsigned short*)alloc(2048ull * 1024 * 2);
  unsigned short* w_gate = (unsigned short*)alloc(2048ull * 1024 * 2);
  unsigned short* w_dt   = (unsigned short*)alloc(2048ull * 2048 * 2);
  unsigned short* w_out  = (unsigned short*)alloc(1024ull * 2048 * 2);
  unsigned short* w_g    = (unsigned short*)alloc(2816ull * 1024 * 2);
  unsigned short* w_u    = (unsigned short*)alloc(2816ull * 1024 * 2);
  unsigned short* w_d    = (unsigned short*)alloc(1024ull * 2752 * 2);

  float* Pb = big;                       // 32*2*2048*16 = 2M floats
  float* Sb = big + 2097152;
  float* Hb = big + 4194304;

  auto cvt = [&](const float* s, unsigned short* dst, int rows, int cols, int dst_rows) {
    int ng = dst_rows * (cols / 4);
    cvt_bf16<<<(ng + 255) / 256, 256, 0, stream>>>(s, dst, rows, cols / 4, dst_rows);
  };
  cvt(in_proj_w, w_in, 2048, 1024, 2048);
  cvt(gate_w,    w_gate, 2048, 1024, 2048);
  cvt(dt_w,      w_dt, 2048, 2048, 2048);
  cvt(out_w,     w_out, 1024, 2048, 1024);
  cvt(ffn_g,     w_g, 2752, 1024, 2816);
  cvt(ffn_u,     w_u, 2752, 1024, 2816);
  cvt(ffn_d,     w_d, 1024, 2752, 1024);

  // 1) h = rmsnorm(x) -> bf16
  rmsnorm_bf16<<<2048, 256, 0, stream>>>(x, norm1_w, h_bf);
  // 2) zg = h @ [in_proj; gate_proj]^T  (N=4096)
  gemm_bt<0><<<dim3(32, 16), 256, 0, stream>>>(h_bf, w_in, w_gate, 16, 1024, big, 4096, nullptr);
  // 3) z = z * sigmoid(gate)
  zfuse<<<4096, 256, 0, stream>>>(big, z32, zbf);
  // 4) dt = softplus(z @ dt_w^T + dt_b)
  gemm_bt<1><<<dim3(16, 16), 256, 0, stream>>>(zbf, w_dt, w_dt, 16, 2048, dt32, 2048, dt_b);
  // 5) BC = z @ x_proj^T
  xproj<<<1024, 256, 0, stream>>>(z32, x_proj_w, bc);
  // 6) chunked selective scan -> y (bf16)
  scan_phase1<<<dim3(8, 32, 2), 256, 0, stream>>>(dt32, z32, bc, A_log, Pb, Sb);
  scan_phase2<<<256, 256, 0, stream>>>(Pb, Sb, Hb);
  scan_phase3<<<dim3(8, 32, 2), 256, 0, stream>>>(dt32, z32, bc, A_log, Dp, Hb, ybf);
  // 7) x2 = x + y @ out_proj^T
  gemm_bt<2><<<dim3(8, 16), 256, 0, stream>>>(ybf, w_out, w_out, 8, 2048, x2, 1024, x);
  // 8) hn = rmsnorm(x2) -> bf16
  rmsnorm_bf16<<<2048, 256, 0, stream>>>(x2, ffn_nw, hn_bf);
  // 9) gu = hn @ [ffn_gate; ffn_up]^T  (N=2*2816 padded)
  gemm_bt<0><<<dim3(44, 16), 256, 0, stream>>>(hn_bf, w_g, w_u, 22, 1024, big, 5632, nullptr);
  // 10) act = silu(g) * u -> bf16
  actfuse<<<5504, 256, 0, stream>>>(big, act_bf);
  // 11) out = x2 + act @ ffn_down^T
  gemm_bt<2><<<dim3(8, 16), 256, 0, stream>>>(act_bf, w_d, w_d, 8, 2752, out, 1024, x2);
}

// Round 4
// 522.309 us; speedup vs baseline: 1.4657x; 1.0384x over previous
//
#include <hip/hip_runtime.h>
#include <cstdint>
#include <cstddef>

// ---------------------------------------------------------------------------
// Mamba-style prelude block on MI355X (gfx950).
// Round 4: xproj (86 us) was address-divergence-bound (each wave-load fanned
// out to 32 cache lines; VALUBusy 6% regardless of occupancy). Killed the
// kernel entirely: BC = z @ x_proj^T is now fused into the dt MFMA GEMM as an
// extra 128-col block column (x_proj_w padded 32->128 rows, bf16), writing a
// [2048][128] bc buffer. Scan reads B/C at row-stride 128.
// ---------------------------------------------------------------------------

#define BM 128
#define BN 128
#define BK 32

typedef __attribute__((ext_vector_type(8))) short short8;   // 8 bf16 (4 VGPRs)
typedef __attribute__((ext_vector_type(4))) float floatx4;  // 4 fp32 acc

__device__ __forceinline__ unsigned short f2bf(float f) {
  unsigned int u = __builtin_bit_cast(unsigned int, f);
  u = u + 0x7fffu + ((u >> 16) & 1u);   // round-to-nearest-even
  return (unsigned short)(u >> 16);
}

__device__ __forceinline__ void async_copy16(const unsigned short* g, unsigned short* l) {
  __builtin_amdgcn_global_load_lds(
      (__attribute__((address_space(1))) void*)(const_cast<unsigned short*>(g)),
      (__attribute__((address_space(3))) void*)(l), 16, 0, 0);
}

// ---------------------------------------------------------------------------
// fp32 -> bf16 weight conversion with optional row padding (zeros).
// ---------------------------------------------------------------------------
__global__ void cvt_bf16(const float* __restrict__ src, unsigned short* __restrict__ dst,
                         int rows, int cols4, int dst_rows) {
  int i = blockIdx.x * blockDim.x + threadIdx.x;
  int total = dst_rows * cols4;
  if (i >= total) return;
  int r = i / cols4, c = i - r * cols4;
  ushort4 o = {0, 0, 0, 0};
  if (r < rows) {
    float4 v = *(const float4*)&src[((size_t)r * cols4 + c) * 4];
    o.x = f2bf(v.x); o.y = f2bf(v.y); o.z = f2bf(v.z); o.w = f2bf(v.w);
  }
  *(ushort4*)&dst[((size_t)r * cols4 + c) * 4] = o;
}

// ---------------------------------------------------------------------------
// RMSNorm: one block (256 thr) per row of D=1024 fp32, writes bf16.
// ---------------------------------------------------------------------------
__global__ __launch_bounds__(256) void rmsnorm_bf16(
    const float* __restrict__ x, const float* __restrict__ w,
    unsigned short* __restrict__ out) {
  const int D = 1024;
  int row = blockIdx.x;
  int t = threadIdx.x;
  const float* xr = x + (size_t)row * D;
  float4 v = *(const float4*)&xr[t * 4];
  float ss = v.x * v.x + v.y * v.y + v.z * v.z + v.w * v.w;
#pragma unroll
  for (int m = 1; m < 64; m <<= 1) ss += __shfl_xor(ss, m);
  __shared__ float ws_[4];
  if ((t & 63) == 0) ws_[t >> 6] = ss;
  __syncthreads();
  float tot = ws_[0] + ws_[1] + ws_[2] + ws_[3];
  float scale = rsqrtf(tot * (1.0f / D) + 1e-6f);
  ushort4 o;
  o.x = f2bf(v.x * scale * w[t * 4 + 0]);
  o.y = f2bf(v.y * scale * w[t * 4 + 1]);
  o.z = f2bf(v.z * scale * w[t * 4 + 2]);
  o.w = f2bf(v.w * scale * w[t * 4 + 3]);
  *(ushort4*)&out[(size_t)row * D + t * 4] = o;
}

// ---------------------------------------------------------------------------
// bf16 MFMA GEMM, C = A @ W^T. 128x128 tile, BK=32, m97 pattern.
// EPI 0: plain store.
// EPI 1: bn<n1_blocks: softplus(acc + aux[gc]) -> C.
//        bn>=n1_blocks: plain acc -> C2[gr*128 + local_col]  (fused x_proj).
// EPI 2: acc + aux[gr*ldc+gc] -> C (residual).
// ---------------------------------------------------------------------------
template <int EPI>
__global__ __launch_bounds__(256, 2) void gemm_bt(
    const unsigned short* __restrict__ A,
    const unsigned short* __restrict__ W1,
    const unsigned short* __restrict__ W2,
    int n1_blocks, int K,
    float* __restrict__ C, int ldc,
    const float* __restrict__ aux,
    float* __restrict__ C2) {
  __shared__ __align__(16) unsigned short As[BM * BK];
  __shared__ __align__(16) unsigned short Bs[BN * BK];
  const int tid = threadIdx.x;
  const int wave = tid >> 6, lane = tid & 63;
  const int bn = blockIdx.x, bm = blockIdx.y;
  const unsigned short* W;
  int wrow0;
  if (bn < n1_blocks) { W = W1; wrow0 = bn * BN; }
  else                { W = W2; wrow0 = (bn - n1_blocks) * BN; }
  const int m0 = bm * BM;
  const int wm = wave >> 1, wn = wave & 1;
  const int l15 = lane & 15, quad = lane >> 4;

  floatx4 acc[4][4] = {};

  const int c0 = wave * 64 + lane;
  const int r0 = c0 >> 2, k0off = (c0 & 3) * 8;
  const int c1 = c0 + 256;
  const int r1 = c1 >> 2, k1off = (c1 & 3) * 8;

  const int nk = K / BK;
  for (int kt = 0; kt < nk; ++kt) {
    __syncthreads();
    const int kb = kt * BK;
    async_copy16(A + (size_t)(m0 + r0) * K + kb + k0off, &As[c0 * 8]);
    async_copy16(A + (size_t)(m0 + r1) * K + kb + k1off, &As[c1 * 8]);
    async_copy16(W + (size_t)(wrow0 + r0) * K + kb + k0off, &Bs[c0 * 8]);
    async_copy16(W + (size_t)(wrow0 + r1) * K + kb + k1off, &Bs[c1 * 8]);
    __syncthreads();

    short8 af[4], bf[4];
#pragma unroll
    for (int i = 0; i < 4; ++i)
      af[i] = *(const short8*)&As[(wm * 64 + i * 16 + l15) * BK + quad * 8];
#pragma unroll
    for (int j = 0; j < 4; ++j)
      bf[j] = *(const short8*)&Bs[(wn * 64 + j * 16 + l15) * BK + quad * 8];
#pragma unroll
    for (int i = 0; i < 4; ++i)
#pragma unroll
      for (int j = 0; j < 4; ++j)
        acc[i][j] = __builtin_amdgcn_mfma_f32_16x16x32_bf16(af[i], bf[j], acc[i][j], 0, 0, 0);
  }

  const bool alt = (EPI == 1) && (bn >= n1_blocks);
#pragma unroll
  for (int i = 0; i < 4; ++i)
#pragma unroll
    for (int j = 0; j < 4; ++j)
#pragma unroll
      for (int r = 0; r < 4; ++r) {
        int gr = m0 + wm * 64 + i * 16 + quad * 4 + r;
        int lc = wn * 64 + j * 16 + l15;           // col within the 128 tile
        int gc = bn * BN + lc;
        float v = acc[i][j][r];
        if (alt) {
          C2[(size_t)gr * 128 + lc] = v;           // fused x_proj -> bc128
        } else if (EPI == 1) {
          v += aux[gc];
          v = fmaxf(v, 0.0f) + log1pf(__expf(-fabsf(v)));
          C[(size_t)gr * ldc + gc] = v;
        } else if (EPI == 2) {
          v += aux[(size_t)gr * ldc + gc];
          C[(size_t)gr * ldc + gc] = v;
        } else {
          C[(size_t)gr * ldc + gc] = v;
        }
      }
}

// ---------------------------------------------------------------------------
// z = z_raw * sigmoid(gate_raw); writes fp32 (for scan) + bf16 (for dt GEMM).
// ---------------------------------------------------------------------------
__global__ void zfuse(const float* __restrict__ zg, float* __restrict__ z32,
                      unsigned short* __restrict__ zbf) {
  int i = blockIdx.x * blockDim.x + threadIdx.x;
  int row = i >> 9, c4 = i & 511;
  float4 zr = *(const float4*)&zg[(size_t)row * 4096 + c4 * 4];
  float4 gr = *(const float4*)&zg[(size_t)row * 4096 + 2048 + c4 * 4];
  float4 o;
  o.x = zr.x / (1.0f + __expf(-gr.x));
  o.y = zr.y / (1.0f + __expf(-gr.y));
  o.z = zr.z / (1.0f + __expf(-gr.z));
  o.w = zr.w / (1.0f + __expf(-gr.w));
  *(float4*)&z32[(size_t)row * 2048 + c4 * 4] = o;
  ushort4 ob;
  ob.x = f2bf(o.x); ob.y = f2bf(o.y); ob.z = f2bf(o.z); ob.w = f2bf(o.w);
  *(ushort4*)&zbf[(size_t)row * 2048 + c4 * 4] = ob;
}

// ---------------------------------------------------------------------------
// Chunked selective scan. T=1024 = 32 chunks x 32 steps.
// bc128: [2048][128] rows = (b*1024+t), cols 0..15 = B, 16..31 = C.
// ---------------------------------------------------------------------------
__device__ __forceinline__ void stage_bc(const float* __restrict__ bc128,
                                         int b, int c, float* bcs, int tid) {
  // 32 rows x 32 cols from row-stride-128 into LDS stride-32.
  int row = tid >> 3, c4 = tid & 7;
  const float* src = bc128 + ((size_t)b * 1024 + c * 32 + row) * 128 + c4 * 4;
  *(float4*)&bcs[row * 32 + c4 * 4] = *(const float4*)src;
}

__global__ __launch_bounds__(256) void scan_phase1(
    const float* __restrict__ dt, const float* __restrict__ z,
    const float* __restrict__ bc128, const float* __restrict__ A_log,
    float* __restrict__ P, float* __restrict__ S) {
  const int d = blockIdx.x * 256 + threadIdx.x;
  const int c = blockIdx.y, b = blockIdx.z;
  __shared__ float bcs[1024];  // 32 t x (16 B | 16 C)
  stage_bc(bc128, b, c, bcs, threadIdx.x);
  __syncthreads();
  float A2[16];
#pragma unroll
  for (int n = 0; n < 16; ++n) A2[n] = -__expf(A_log[d * 16 + n]) * 1.44269504f;
  float p[16], s[16];
#pragma unroll
  for (int n = 0; n < 16; ++n) { p[n] = 1.0f; s[n] = 0.0f; }
  const size_t base = ((size_t)b * 1024 + c * 32) * 2048 + d;
#pragma unroll 4
  for (int t = 0; t < 32; ++t) {
    float dtv = dt[base + (size_t)t * 2048];
    float zv  = z [base + (size_t)t * 2048];
    float dtz = dtv * zv;
#pragma unroll
    for (int n = 0; n < 16; ++n) {
      float dA = exp2f(dtv * A2[n]);
      s[n] = __builtin_fmaf(dA, s[n], dtz * bcs[t * 32 + n]);
      p[n] *= dA;
    }
  }
  float* Pp = P + (((size_t)c * 2 + b) * 2048 + d) * 16;
  float* Sp = S + (((size_t)c * 2 + b) * 2048 + d) * 16;
#pragma unroll
  for (int n = 0; n < 16; ++n) { Pp[n] = p[n]; Sp[n] = s[n]; }
}

// Phase 2: per (b,d,n) combine across chunks; H[c] = state entering chunk c.
__global__ __launch_bounds__(256) void scan_phase2(
    const float* __restrict__ P, const float* __restrict__ S,
    float* __restrict__ H) {
  int i = blockIdx.x * 256 + threadIdx.x;  // i = (b*2048+d)*16+n
  float h = 0.0f;
#pragma unroll
  for (int c = 0; c < 32; ++c) {
    size_t idx = (size_t)c * 65536 + i;
    H[idx] = h;
    h = __builtin_fmaf(P[idx], h, S[idx]);
  }
}

// Phase 3: recompute within chunk from H; y = sum_n h*C + z*Dp -> bf16.
__global__ __launch_bounds__(256) void scan_phase3(
    const float* __restrict__ dt, const float* __restrict__ z,
    const float* __restrict__ bc128, const float* __restrict__ A_log,
    const float* __restrict__ Dp, const float* __restrict__ H,
    unsigned short* __restrict__ ybf) {
  const int d = blockIdx.x * 256 + threadIdx.x;
  const int c = blockIdx.y, b = blockIdx.z;
  __shared__ float bcs[1024];
  stage_bc(bc128, b, c, bcs, threadIdx.x);
  __syncthreads();
  float A2[16];
#pragma unroll
  for (int n = 0; n < 16; ++n) A2[n] = -__expf(A_log[d * 16 + n]) * 1.44269504f;
  float h[16];
  const float* Hp = H + (((size_t)c * 2 + b) * 2048 + d) * 16;
#pragma unroll
  for (int n = 0; n < 16; ++n) h[n] = Hp[n];
  const float Dd = Dp[d];
  const size_t base = ((size_t)b * 1024 + c * 32) * 2048 + d;
#pragma unroll 4
  for (int t = 0; t < 32; ++t) {
    float dtv = dt[base + (size_t)t * 2048];
    float zv  = z [base + (size_t)t * 2048];
    float dtz = dtv * zv;
    float y = zv * Dd;
#pragma unroll
    for (int n = 0; n < 16; ++n) {
      float dA = exp2f(dtv * A2[n]);
      h[n] = __builtin_fmaf(dA, h[n], dtz * bcs[t * 32 + n]);
      y = __builtin_fmaf(h[n], bcs[t * 32 + 16 + n], y);
    }
    ybf[base + (size_t)t * 2048] = f2bf(y);
  }
}

// ---------------------------------------------------------------------------
// act = silu(g) * u from padded gu buffer [2048][5632].
// ---------------------------------------------------------------------------
__global__ void actfuse(const float* __restrict__ gu, unsigned short* __restrict__ act) {
  int i = blockIdx.x * blockDim.x + threadIdx.x;
  int row = i / 688, c4 = i - row * 688;
  float4 g = *(const float4*)&gu[(size_t)row * 5632 + c4 * 4];
  float4 u = *(const float4*)&gu[(size_t)row * 5632 + 2816 + c4 * 4];
  ushort4 o;
  o.x = f2bf(g.x / (1.0f + __expf(-g.x)) * u.x);
  o.y = f2bf(g.y / (1.0f + __expf(-g.y)) * u.y);
  o.z = f2bf(g.z / (1.0f + __expf(-g.z)) * u.z);
  o.w = f2bf(g.w / (1.0f + __expf(-g.w)) * u.w);
  *(ushort4*)&act[(size_t)row * 2752 + c4 * 4] = o;
}

// ---------------------------------------------------------------------------
extern "C" void kernel_launch(void* const* d_in, const int* in_sizes, int n_in,
                              void* d_out, int out_size, void* d_ws, size_t ws_size,
                              hipStream_t stream) {
  const float* x         = (const float*)d_in[0];
  const float* norm1_w   = (const float*)d_in[1];
  const float* in_proj_w = (const float*)d_in[2];
  const float* gate_w    = (const float*)d_in[3];
  const float* dt_w      = (const float*)d_in[4];
  const float* dt_b      = (const float*)d_in[5];
  const float* x_proj_w  = (const float*)d_in[6];
  const float* A_log     = (const float*)d_in[7];
  const float* Dp        = (const float*)d_in[8];
  const float* out_w     = (const float*)d_in[9];
  const float* ffn_nw    = (const float*)d_in[10];
  const float* ffn_g     = (const float*)d_in[11];
  const float* ffn_u     = (const float*)d_in[12];
  const float* ffn_d     = (const float*)d_in[13];
  float* out = (float*)d_out;

  char* p = (char*)d_ws;
  auto alloc = [&](size_t b) { char* r = p; p += (b + 255) & ~(size_t)255; return r; };
  unsigned short* h_bf   = (unsigned short*)alloc(2048ull * 1024 * 2);
  float* big             = (float*)alloc(2048ull * 5632 * 4);  // zg | (P,S,H) | gu
  float* z32             = (float*)alloc(2048ull * 2048 * 4);
  unsigned short* zbf    = (unsigned short*)alloc(2048ull * 2048 * 2);
  float* dt32            = (float*)alloc(2048ull * 2048 * 4);
  float* bc128           = (float*)alloc(2048ull * 128 * 4);
  unsigned short* ybf    = (unsigned short*)alloc(2048ull * 2048 * 2);
  float* x2              = (float*)alloc(2048ull * 1024 * 4);
  unsigned short* hn_bf  = (unsigned short*)alloc(2048ull * 1024 * 2);
  unsigned short* act_bf = (unsigned short*)alloc(2048ull * 2752 * 2);
  unsigned short* w_in   = (unsigned short*)alloc(2048ull * 1024 * 2);
  unsigned short* w_gate = (unsigned short*)alloc(2048ull * 1024 * 2);
  unsigned short* w_dt   = (unsigned short*)alloc(2048ull * 2048 * 2);
  unsigned short* w_xp   = (unsigned short*)alloc(128ull * 2048 * 2);
  unsigned short* w_out  = (unsigned short*)alloc(1024ull * 2048 * 2);
  unsigned short* w_g    = (unsigned short*)alloc(2816ull * 1024 * 2);
  unsigned short* w_u    = (unsigned short*)alloc(2816ull * 1024 * 2);
  unsigned short* w_d    = (unsigned short*)alloc(1024ull * 2752 * 2);

  float* Pb = big;                       // 32*2*2048*16 = 2M floats
  float* Sb = big + 2097152;
  float* Hb = big + 4194304;

  auto cvt = [&](const float* s, unsigned short* dst, int rows, int cols, int dst_rows) {
    int ng = dst_rows * (cols / 4);
    cvt_bf16<<<(ng + 255) / 256, 256, 0, stream>>>(s, dst, rows, cols / 4, dst_rows);
  };
  cvt(in_proj_w, w_in, 2048, 1024, 2048);
  cvt(gate_w,    w_gate, 2048, 1024, 2048);
  cvt(dt_w,      w_dt, 2048, 2048, 2048);
  cvt(x_proj_w,  w_xp, 32, 2048, 128);      // pad 32 -> 128 rows with zeros
  cvt(out_w,     w_out, 1024, 2048, 1024);
  cvt(ffn_g,     w_g, 2752, 1024, 2816);
  cvt(ffn_u,     w_u, 2752, 1024, 2816);
  cvt(ffn_d,     w_d, 1024, 2752, 1024);

  // 1) h = rmsnorm(x) -> bf16
  rmsnorm_bf16<<<2048, 256, 0, stream>>>(x, norm1_w, h_bf);
  // 2) zg = h @ [in_proj; gate_proj]^T  (N=4096)
  gemm_bt<0><<<dim3(32, 16), 256, 0, stream>>>(h_bf, w_in, w_gate, 16, 1024, big, 4096, nullptr, nullptr);
  // 3) z = z * sigmoid(gate)
  zfuse<<<4096, 256, 0, stream>>>(big, z32, zbf);
  // 4) dt = softplus(z @ dt_w^T + dt_b)  ++  BC = z @ x_proj^T (fused col-block)
  gemm_bt<1><<<dim3(17, 16), 256, 0, stream>>>(zbf, w_dt, w_xp, 16, 2048, dt32, 2048, dt_b, bc128);
  // 5) chunked selective scan -> y (bf16)
  scan_phase1<<<dim3(8, 32, 2), 256, 0, stream>>>(dt32, z32, bc128, A_log, Pb, Sb);
  scan_phase2<<<256, 256, 0, stream>>>(Pb, Sb, Hb);
  scan_phase3<<<dim3(8, 32, 2), 256, 0, stream>>>(dt32, z32, bc128, A_log, Dp, Hb, ybf);
  // 6) x2 = x + y @ out_proj^T
  gemm_bt<2><<<dim3(8, 16), 256, 0, stream>>>(ybf, w_out, w_out, 8, 2048, x2, 1024, x, nullptr);
  // 7) hn = rmsnorm(x2) -> bf16
  rmsnorm_bf16<<<2048, 256, 0, stream>>>(x2, ffn_nw, hn_bf);
  // 8) gu = hn @ [ffn_gate; ffn_up]^T  (N=2*2816 padded)
  gemm_bt<0><<<dim3(44, 16), 256, 0, stream>>>(hn_bf, w_g, w_u, 22, 1024, big, 5632, nullptr, nullptr);
  // 9) act = silu(g) * u -> bf16
  actfuse<<<5504, 256, 0, stream>>>(big, act_bf);
  // 10) out = x2 + act @ ffn_down^T
  gemm_bt<2><<<dim3(8, 16), 256, 0, stream>>>(act_bf, w_d, w_d, 8, 2752, out, 1024, x2, nullptr);
}

// Round 5
// 483.327 us; speedup vs baseline: 1.5839x; 1.0807x over previous
//
#include <hip/hip_runtime.h>
#include <cstdint>
#include <cstddef>

// ---------------------------------------------------------------------------
// Mamba-style prelude block on MI355X (gfx950).
// Round 5: round-4's dt+xproj fusion regressed dt 86->149 us because grid
// (17,16) broke the XCD round-robin locality (XCD=(bn+bm)%8 -> every XCD
// touched all of A and W; FETCH 68 MB = 4x unique). Fixes:
//   - dt launch grid (16,17): extra xproj block-row in Y keeps XCD=bn%8.
//   - ffn gate/up: 1D grid 768 with explicit swizzle bn=(l&7)+8*((l>>3)%6)
//     so each XCD owns bn = xcd (mod 8) (~2.8 MB W footprint vs 5.5).
//   - __launch_bounds__(256,4): 4 blocks/CU (VGPR 56+64agpr=120<=128).
// ---------------------------------------------------------------------------

#define BM 128
#define BN 128
#define BK 32

typedef __attribute__((ext_vector_type(8))) short short8;   // 8 bf16 (4 VGPRs)
typedef __attribute__((ext_vector_type(4))) float floatx4;  // 4 fp32 acc

__device__ __forceinline__ unsigned short f2bf(float f) {
  unsigned int u = __builtin_bit_cast(unsigned int, f);
  u = u + 0x7fffu + ((u >> 16) & 1u);   // round-to-nearest-even
  return (unsigned short)(u >> 16);
}

__device__ __forceinline__ void async_copy16(const unsigned short* g, unsigned short* l) {
  __builtin_amdgcn_global_load_lds(
      (__attribute__((address_space(1))) void*)(const_cast<unsigned short*>(g)),
      (__attribute__((address_space(3))) void*)(l), 16, 0, 0);
}

// ---------------------------------------------------------------------------
// fp32 -> bf16 weight conversion with optional row padding (zeros).
// ---------------------------------------------------------------------------
__global__ void cvt_bf16(const float* __restrict__ src, unsigned short* __restrict__ dst,
                         int rows, int cols4, int dst_rows) {
  int i = blockIdx.x * blockDim.x + threadIdx.x;
  int total = dst_rows * cols4;
  if (i >= total) return;
  int r = i / cols4, c = i - r * cols4;
  ushort4 o = {0, 0, 0, 0};
  if (r < rows) {
    float4 v = *(const float4*)&src[((size_t)r * cols4 + c) * 4];
    o.x = f2bf(v.x); o.y = f2bf(v.y); o.z = f2bf(v.z); o.w = f2bf(v.w);
  }
  *(ushort4*)&dst[((size_t)r * cols4 + c) * 4] = o;
}

// ---------------------------------------------------------------------------
// RMSNorm: one block (256 thr) per row of D=1024 fp32, writes bf16.
// ---------------------------------------------------------------------------
__global__ __launch_bounds__(256) void rmsnorm_bf16(
    const float* __restrict__ x, const float* __restrict__ w,
    unsigned short* __restrict__ out) {
  const int D = 1024;
  int row = blockIdx.x;
  int t = threadIdx.x;
  const float* xr = x + (size_t)row * D;
  float4 v = *(const float4*)&xr[t * 4];
  float ss = v.x * v.x + v.y * v.y + v.z * v.z + v.w * v.w;
#pragma unroll
  for (int m = 1; m < 64; m <<= 1) ss += __shfl_xor(ss, m);
  __shared__ float ws_[4];
  if ((t & 63) == 0) ws_[t >> 6] = ss;
  __syncthreads();
  float tot = ws_[0] + ws_[1] + ws_[2] + ws_[3];
  float scale = rsqrtf(tot * (1.0f / D) + 1e-6f);
  ushort4 o;
  o.x = f2bf(v.x * scale * w[t * 4 + 0]);
  o.y = f2bf(v.y * scale * w[t * 4 + 1]);
  o.z = f2bf(v.z * scale * w[t * 4 + 2]);
  o.w = f2bf(v.w * scale * w[t * 4 + 3]);
  *(ushort4*)&out[(size_t)row * D + t * 4] = o;
}

// ---------------------------------------------------------------------------
// bf16 MFMA GEMM, C = A @ W^T. 128x128 tile, BK=32, m97 pattern.
// MAP 0: bn=blockIdx.x, bm=blockIdx.y (use when gridDim.x % 8 == 0).
// MAP 1: dt+xproj: y<gridDim.y-1 -> (bn=x, bm=y); y==last -> bn=n1_blocks,
//        bm=x  (keeps XCD = x%8 for the main dt grid).
// MAP 2: 1D swizzle: l=blockIdx.x; bn=(l&7)+8*((l>>3)%6); bm=(l>>3)/6;
//        return if bn >= ncols. (each XCD owns bn = xcd mod 8)
// EPI 0: plain store. EPI 1: softplus(acc+aux[gc]) (dt) / plain->C2 (xproj).
// EPI 2: acc + aux residual.
// ---------------------------------------------------------------------------
template <int EPI, int MAP>
__global__ __launch_bounds__(256, 4) void gemm_bt(
    const unsigned short* __restrict__ A,
    const unsigned short* __restrict__ W1,
    const unsigned short* __restrict__ W2,
    int n1_blocks, int ncols, int K,
    float* __restrict__ C, int ldc,
    const float* __restrict__ aux,
    float* __restrict__ C2) {
  __shared__ __align__(16) unsigned short As[BM * BK];
  __shared__ __align__(16) unsigned short Bs[BN * BK];
  int bn, bm;
  if (MAP == 0) {
    bn = blockIdx.x; bm = blockIdx.y;
  } else if (MAP == 1) {
    if (blockIdx.y < gridDim.y - 1) { bn = blockIdx.x; bm = blockIdx.y; }
    else                            { bn = n1_blocks;  bm = blockIdx.x; }
  } else {
    int l = blockIdx.x, i = l >> 3;
    bn = (l & 7) + 8 * (i % 6);
    bm = i / 6;
    if (bn >= ncols) return;
  }
  const int tid = threadIdx.x;
  const int wave = tid >> 6, lane = tid & 63;
  const unsigned short* W;
  int wrow0;
  if (bn < n1_blocks) { W = W1; wrow0 = bn * BN; }
  else                { W = W2; wrow0 = (bn - n1_blocks) * BN; }
  const int m0 = bm * BM;
  const int wm = wave >> 1, wn = wave & 1;
  const int l15 = lane & 15, quad = lane >> 4;

  floatx4 acc[4][4] = {};

  const int c0 = wave * 64 + lane;
  const int r0 = c0 >> 2, k0off = (c0 & 3) * 8;
  const int c1 = c0 + 256;
  const int r1 = c1 >> 2, k1off = (c1 & 3) * 8;

  const int nk = K / BK;
  for (int kt = 0; kt < nk; ++kt) {
    __syncthreads();
    const int kb = kt * BK;
    async_copy16(A + (size_t)(m0 + r0) * K + kb + k0off, &As[c0 * 8]);
    async_copy16(A + (size_t)(m0 + r1) * K + kb + k1off, &As[c1 * 8]);
    async_copy16(W + (size_t)(wrow0 + r0) * K + kb + k0off, &Bs[c0 * 8]);
    async_copy16(W + (size_t)(wrow0 + r1) * K + kb + k1off, &Bs[c1 * 8]);
    __syncthreads();

    short8 af[4], bf[4];
#pragma unroll
    for (int i = 0; i < 4; ++i)
      af[i] = *(const short8*)&As[(wm * 64 + i * 16 + l15) * BK + quad * 8];
#pragma unroll
    for (int j = 0; j < 4; ++j)
      bf[j] = *(const short8*)&Bs[(wn * 64 + j * 16 + l15) * BK + quad * 8];
#pragma unroll
    for (int i = 0; i < 4; ++i)
#pragma unroll
      for (int j = 0; j < 4; ++j)
        acc[i][j] = __builtin_amdgcn_mfma_f32_16x16x32_bf16(af[i], bf[j], acc[i][j], 0, 0, 0);
  }

  const bool alt = (EPI == 1) && (bn >= n1_blocks);
#pragma unroll
  for (int i = 0; i < 4; ++i)
#pragma unroll
    for (int j = 0; j < 4; ++j)
#pragma unroll
      for (int r = 0; r < 4; ++r) {
        int gr = m0 + wm * 64 + i * 16 + quad * 4 + r;
        int lc = wn * 64 + j * 16 + l15;           // col within the 128 tile
        int gc = bn * BN + lc;
        float v = acc[i][j][r];
        if (alt) {
          C2[(size_t)gr * 128 + lc] = v;           // fused x_proj -> bc128
        } else if (EPI == 1) {
          v += aux[gc];
          v = fmaxf(v, 0.0f) + log1pf(__expf(-fabsf(v)));
          C[(size_t)gr * ldc + gc] = v;
        } else if (EPI == 2) {
          v += aux[(size_t)gr * ldc + gc];
          C[(size_t)gr * ldc + gc] = v;
        } else {
          C[(size_t)gr * ldc + gc] = v;
        }
      }
}

// ---------------------------------------------------------------------------
// z = z_raw * sigmoid(gate_raw); writes fp32 (for scan) + bf16 (for dt GEMM).
// ---------------------------------------------------------------------------
__global__ void zfuse(const float* __restrict__ zg, float* __restrict__ z32,
                      unsigned short* __restrict__ zbf) {
  int i = blockIdx.x * blockDim.x + threadIdx.x;
  int row = i >> 9, c4 = i & 511;
  float4 zr = *(const float4*)&zg[(size_t)row * 4096 + c4 * 4];
  float4 gr = *(const float4*)&zg[(size_t)row * 4096 + 2048 + c4 * 4];
  float4 o;
  o.x = zr.x / (1.0f + __expf(-gr.x));
  o.y = zr.y / (1.0f + __expf(-gr.y));
  o.z = zr.z / (1.0f + __expf(-gr.z));
  o.w = zr.w / (1.0f + __expf(-gr.w));
  *(float4*)&z32[(size_t)row * 2048 + c4 * 4] = o;
  ushort4 ob;
  ob.x = f2bf(o.x); ob.y = f2bf(o.y); ob.z = f2bf(o.z); ob.w = f2bf(o.w);
  *(ushort4*)&zbf[(size_t)row * 2048 + c4 * 4] = ob;
}

// ---------------------------------------------------------------------------
// Chunked selective scan. T=1024 = 32 chunks x 32 steps.
// bc128: [2048][128] rows = (b*1024+t), cols 0..15 = B, 16..31 = C.
// ---------------------------------------------------------------------------
__device__ __forceinline__ void stage_bc(const float* __restrict__ bc128,
                                         int b, int c, float* bcs, int tid) {
  int row = tid >> 3, c4 = tid & 7;
  const float* src = bc128 + ((size_t)b * 1024 + c * 32 + row) * 128 + c4 * 4;
  *(float4*)&bcs[row * 32 + c4 * 4] = *(const float4*)src;
}

__global__ __launch_bounds__(256) void scan_phase1(
    const float* __restrict__ dt, const float* __restrict__ z,
    const float* __restrict__ bc128, const float* __restrict__ A_log,
    float* __restrict__ P, float* __restrict__ S) {
  const int d = blockIdx.x * 256 + threadIdx.x;
  const int c = blockIdx.y, b = blockIdx.z;
  __shared__ float bcs[1024];  // 32 t x (16 B | 16 C)
  stage_bc(bc128, b, c, bcs, threadIdx.x);
  __syncthreads();
  float A2[16];
#pragma unroll
  for (int n = 0; n < 16; ++n) A2[n] = -__expf(A_log[d * 16 + n]) * 1.44269504f;
  float p[16], s[16];
#pragma unroll
  for (int n = 0; n < 16; ++n) { p[n] = 1.0f; s[n] = 0.0f; }
  const size_t base = ((size_t)b * 1024 + c * 32) * 2048 + d;
#pragma unroll 4
  for (int t = 0; t < 32; ++t) {
    float dtv = dt[base + (size_t)t * 2048];
    float zv  = z [base + (size_t)t * 2048];
    float dtz = dtv * zv;
#pragma unroll
    for (int n = 0; n < 16; ++n) {
      float dA = exp2f(dtv * A2[n]);
      s[n] = __builtin_fmaf(dA, s[n], dtz * bcs[t * 32 + n]);
      p[n] *= dA;
    }
  }
  float* Pp = P + (((size_t)c * 2 + b) * 2048 + d) * 16;
  float* Sp = S + (((size_t)c * 2 + b) * 2048 + d) * 16;
#pragma unroll
  for (int n = 0; n < 16; ++n) { Pp[n] = p[n]; Sp[n] = s[n]; }
}

// Phase 2: per (b,d,n) combine across chunks; H[c] = state entering chunk c.
__global__ __launch_bounds__(256) void scan_phase2(
    const float* __restrict__ P, const float* __restrict__ S,
    float* __restrict__ H) {
  int i = blockIdx.x * 256 + threadIdx.x;  // i = (b*2048+d)*16+n
  float h = 0.0f;
#pragma unroll
  for (int c = 0; c < 32; ++c) {
    size_t idx = (size_t)c * 65536 + i;
    H[idx] = h;
    h = __builtin_fmaf(P[idx], h, S[idx]);
  }
}

// Phase 3: recompute within chunk from H; y = sum_n h*C + z*Dp -> bf16.
__global__ __launch_bounds__(256) void scan_phase3(
    const float* __restrict__ dt, const float* __restrict__ z,
    const float* __restrict__ bc128, const float* __restrict__ A_log,
    const float* __restrict__ Dp, const float* __restrict__ H,
    unsigned short* __restrict__ ybf) {
  const int d = blockIdx.x * 256 + threadIdx.x;
  const int c = blockIdx.y, b = blockIdx.z;
  __shared__ float bcs[1024];
  stage_bc(bc128, b, c, bcs, threadIdx.x);
  __syncthreads();
  float A2[16];
#pragma unroll
  for (int n = 0; n < 16; ++n) A2[n] = -__expf(A_log[d * 16 + n]) * 1.44269504f;
  float h[16];
  const float* Hp = H + (((size_t)c * 2 + b) * 2048 + d) * 16;
#pragma unroll
  for (int n = 0; n < 16; ++n) h[n] = Hp[n];
  const float Dd = Dp[d];
  const size_t base = ((size_t)b * 1024 + c * 32) * 2048 + d;
#pragma unroll 4
  for (int t = 0; t < 32; ++t) {
    float dtv = dt[base + (size_t)t * 2048];
    float zv  = z [base + (size_t)t * 2048];
    float dtz = dtv * zv;
    float y = zv * Dd;
#pragma unroll
    for (int n = 0; n < 16; ++n) {
      float dA = exp2f(dtv * A2[n]);
      h[n] = __builtin_fmaf(dA, h[n], dtz * bcs[t * 32 + n]);
      y = __builtin_fmaf(h[n], bcs[t * 32 + 16 + n], y);
    }
    ybf[base + (size_t)t * 2048] = f2bf(y);
  }
}

// ---------------------------------------------------------------------------
// act = silu(g) * u from padded gu buffer [2048][5632].
// ---------------------------------------------------------------------------
__global__ void actfuse(const float* __restrict__ gu, unsigned short* __restrict__ act) {
  int i = blockIdx.x * blockDim.x + threadIdx.x;
  int row = i / 688, c4 = i - row * 688;
  float4 g = *(const float4*)&gu[(size_t)row * 5632 + c4 * 4];
  float4 u = *(const float4*)&gu[(size_t)row * 5632 + 2816 + c4 * 4];
  ushort4 o;
  o.x = f2bf(g.x / (1.0f + __expf(-g.x)) * u.x);
  o.y = f2bf(g.y / (1.0f + __expf(-g.y)) * u.y);
  o.z = f2bf(g.z / (1.0f + __expf(-g.z)) * u.z);
  o.w = f2bf(g.w / (1.0f + __expf(-g.w)) * u.w);
  *(ushort4*)&act[(size_t)row * 2752 + c4 * 4] = o;
}

// ---------------------------------------------------------------------------
extern "C" void kernel_launch(void* const* d_in, const int* in_sizes, int n_in,
                              void* d_out, int out_size, void* d_ws, size_t ws_size,
                              hipStream_t stream) {
  const float* x         = (const float*)d_in[0];
  const float* norm1_w   = (const float*)d_in[1];
  const float* in_proj_w = (const float*)d_in[2];
  const float* gate_w    = (const float*)d_in[3];
  const float* dt_w      = (const float*)d_in[4];
  const float* dt_b      = (const float*)d_in[5];
  const float* x_proj_w  = (const float*)d_in[6];
  const float* A_log     = (const float*)d_in[7];
  const float* Dp        = (const float*)d_in[8];
  const float* out_w     = (const float*)d_in[9];
  const float* ffn_nw    = (const float*)d_in[10];
  const float* ffn_g     = (const float*)d_in[11];
  const float* ffn_u     = (const float*)d_in[12];
  const float* ffn_d     = (const float*)d_in[13];
  float* out = (float*)d_out;

  char* p = (char*)d_ws;
  auto alloc = [&](size_t b) { char* r = p; p += (b + 255) & ~(size_t)255; return r; };
  unsigned short* h_bf   = (unsigned short*)alloc(2048ull * 1024 * 2);
  float* big             = (float*)alloc(2048ull * 5632 * 4);  // zg | (P,S,H) | gu
  float* z32             = (float*)alloc(2048ull * 2048 * 4);
  unsigned short* zbf    = (unsigned short*)alloc(2048ull * 2048 * 2);
  float* dt32            = (float*)alloc(2048ull * 2048 * 4);
  float* bc128           = (float*)alloc(2048ull * 128 * 4);
  unsigned short* ybf    = (unsigned short*)alloc(2048ull * 2048 * 2);
  float* x2              = (float*)alloc(2048ull * 1024 * 4);
  unsigned short* hn_bf  = (unsigned short*)alloc(2048ull * 1024 * 2);
  unsigned short* act_bf = (unsigned short*)alloc(2048ull * 2752 * 2);
  unsigned short* w_in   = (unsigned short*)alloc(2048ull * 1024 * 2);
  unsigned short* w_gate = (unsigned short*)alloc(2048ull * 1024 * 2);
  unsigned short* w_dt   = (unsigned short*)alloc(2048ull * 2048 * 2);
  unsigned short* w_xp   = (unsigned short*)alloc(128ull * 2048 * 2);
  unsigned short* w_out  = (unsigned short*)alloc(1024ull * 2048 * 2);
  unsigned short* w_g    = (unsigned short*)alloc(2816ull * 1024 * 2);
  unsigned short* w_u    = (unsigned short*)alloc(2816ull * 1024 * 2);
  unsigned short* w_d    = (unsigned short*)alloc(1024ull * 2752 * 2);

  float* Pb = big;                       // 32*2*2048*16 = 2M floats
  float* Sb = big + 2097152;
  float* Hb = big + 4194304;

  auto cvt = [&](const float* s, unsigned short* dst, int rows, int cols, int dst_rows) {
    int ng = dst_rows * (cols / 4);
    cvt_bf16<<<(ng + 255) / 256, 256, 0, stream>>>(s, dst, rows, cols / 4, dst_rows);
  };
  cvt(in_proj_w, w_in, 2048, 1024, 2048);
  cvt(gate_w,    w_gate, 2048, 1024, 2048);
  cvt(dt_w,      w_dt, 2048, 2048, 2048);
  cvt(x_proj_w,  w_xp, 32, 2048, 128);      // pad 32 -> 128 rows with zeros
  cvt(out_w,     w_out, 1024, 2048, 1024);
  cvt(ffn_g,     w_g, 2752, 1024, 2816);
  cvt(ffn_u,     w_u, 2752, 1024, 2816);
  cvt(ffn_d,     w_d, 1024, 2752, 1024);

  // 1) h = rmsnorm(x) -> bf16
  rmsnorm_bf16<<<2048, 256, 0, stream>>>(x, norm1_w, h_bf);
  // 2) zg = h @ [in_proj; gate_proj]^T  (N=4096; 32%8==0 -> MAP0 ok)
  gemm_bt<0, 0><<<dim3(32, 16), 256, 0, stream>>>(h_bf, w_in, w_gate, 16, 0, 1024, big, 4096, nullptr, nullptr);
  // 3) z = z * sigmoid(gate)
  zfuse<<<4096, 256, 0, stream>>>(big, z32, zbf);
  // 4) dt = softplus(z @ dt_w^T + dt_b) ++ BC = z @ x_proj^T (extra row in Y)
  gemm_bt<1, 1><<<dim3(16, 17), 256, 0, stream>>>(zbf, w_dt, w_xp, 16, 0, 2048, dt32, 2048, dt_b, bc128);
  // 5) chunked selective scan -> y (bf16)
  scan_phase1<<<dim3(8, 32, 2), 256, 0, stream>>>(dt32, z32, bc128, A_log, Pb, Sb);
  scan_phase2<<<256, 256, 0, stream>>>(Pb, Sb, Hb);
  scan_phase3<<<dim3(8, 32, 2), 256, 0, stream>>>(dt32, z32, bc128, A_log, Dp, Hb, ybf);
  // 6) x2 = x + y @ out_proj^T  (8%8==0 -> MAP0)
  gemm_bt<2, 0><<<dim3(8, 16), 256, 0, stream>>>(ybf, w_out, w_out, 8, 0, 2048, x2, 1024, x, nullptr);
  // 7) hn = rmsnorm(x2) -> bf16
  rmsnorm_bf16<<<2048, 256, 0, stream>>>(x2, ffn_nw, hn_bf);
  // 8) gu = hn @ [ffn_gate; ffn_up]^T  (44 cols: swizzled 1D grid, 768 blocks)
  gemm_bt<0, 2><<<768, 256, 0, stream>>>(hn_bf, w_g, w_u, 22, 44, 1024, big, 5632, nullptr, nullptr);
  // 9) act = silu(g) * u -> bf16
  actfuse<<<5504, 256, 0, stream>>>(big, act_bf);
  // 10) out = x2 + act @ ffn_down^T
  gemm_bt<2, 0><<<dim3(8, 16), 256, 0, stream>>>(act_bf, w_d, w_d, 8, 0, 2752, out, 1024, x2, nullptr);
}

// Round 6
// 434.093 us; speedup vs baseline: 1.7635x; 1.1134x over previous
//
#include <hip/hip_runtime.h>
#include <cstdint>
#include <cstddef>

// ---------------------------------------------------------------------------
// Mamba-style prelude block on MI355X (gfx950).
// Round 6: GEMMs were grid-limited to ~1 wave/SIMD (OccupancyPercent ~10.5%
// regardless of launch_bounds) -> no wave-level overlap -> MfmaUtil 9%.
//  - K-loop rewritten: double-buffered LDS, stage(kt+1) issued BEFORE
//    compute(kt), single __syncthreads per iter (intra-wave latency hiding).
//  - XOR bank swizzle on 16B chunks (q^=(row>>1)&3) kills the 8-way
//    ds_read_b128 conflicts (SQ_LDS_BANK_CONFLICT was 2.2M/dispatch).
//  - out_proj & ffn_down: split-K x2 (grid 16x16, fp32 partials; reduce
//    folded into rmsnorm_fuse3 / final_add) -> all 256 CUs busy.
//  - zg & gu intermediates stored bf16 from the GEMM epilogue (~70 MB saved).
// ---------------------------------------------------------------------------

#define BM 128
#define BN 128
#define BK 32

typedef __attribute__((ext_vector_type(8))) short short8;   // 8 bf16 (4 VGPRs)
typedef __attribute__((ext_vector_type(4))) float floatx4;  // 4 fp32 acc

__device__ __forceinline__ unsigned short f2bf(float f) {
  unsigned int u = __builtin_bit_cast(unsigned int, f);
  u = u + 0x7fffu + ((u >> 16) & 1u);   // round-to-nearest-even
  return (unsigned short)(u >> 16);
}
__device__ __forceinline__ float bf2f(unsigned short u) {
  return __builtin_bit_cast(float, (unsigned int)u << 16);
}

__device__ __forceinline__ void async_copy16(const unsigned short* g, unsigned short* l) {
  __builtin_amdgcn_global_load_lds(
      (__attribute__((address_space(1))) void*)(const_cast<unsigned short*>(g)),
      (__attribute__((address_space(3))) void*)(l), 16, 0, 0);
}

// ---------------------------------------------------------------------------
__global__ void cvt_bf16(const float* __restrict__ src, unsigned short* __restrict__ dst,
                         int rows, int cols4, int dst_rows) {
  int i = blockIdx.x * blockDim.x + threadIdx.x;
  int total = dst_rows * cols4;
  if (i >= total) return;
  int r = i / cols4, c = i - r * cols4;
  ushort4 o = {0, 0, 0, 0};
  if (r < rows) {
    float4 v = *(const float4*)&src[((size_t)r * cols4 + c) * 4];
    o.x = f2bf(v.x); o.y = f2bf(v.y); o.z = f2bf(v.z); o.w = f2bf(v.w);
  }
  *(ushort4*)&dst[((size_t)r * cols4 + c) * 4] = o;
}

// ---------------------------------------------------------------------------
// RMSNorm: one block per row of D=1024 fp32, writes bf16.
// ---------------------------------------------------------------------------
__global__ __launch_bounds__(256) void rmsnorm_bf16(
    const float* __restrict__ x, const float* __restrict__ w,
    unsigned short* __restrict__ out) {
  int row = blockIdx.x, t = threadIdx.x;
  float4 v = *(const float4*)&x[(size_t)row * 1024 + t * 4];
  float ss = v.x * v.x + v.y * v.y + v.z * v.z + v.w * v.w;
#pragma unroll
  for (int m = 1; m < 64; m <<= 1) ss += __shfl_xor(ss, m);
  __shared__ float ws_[4];
  if ((t & 63) == 0) ws_[t >> 6] = ss;
  __syncthreads();
  float tot = ws_[0] + ws_[1] + ws_[2] + ws_[3];
  float scale = rsqrtf(tot * (1.0f / 1024.0f) + 1e-6f);
  ushort4 o;
  o.x = f2bf(v.x * scale * w[t * 4 + 0]);
  o.y = f2bf(v.y * scale * w[t * 4 + 1]);
  o.z = f2bf(v.z * scale * w[t * 4 + 2]);
  o.w = f2bf(v.w * scale * w[t * 4 + 3]);
  *(ushort4*)&out[(size_t)row * 1024 + t * 4] = o;
}

// ---------------------------------------------------------------------------
// RMSNorm fused with split-K reduce: x2 = x + p0 + p1; hn = rmsnorm(x2)*w.
// ---------------------------------------------------------------------------
__global__ __launch_bounds__(256) void rmsnorm_fuse3(
    const float* __restrict__ x, const float* __restrict__ p,
    const float* __restrict__ w,
    float* __restrict__ x2, unsigned short* __restrict__ outbf) {
  int row = blockIdx.x, t = threadIdx.x;
  size_t off = (size_t)row * 1024 + t * 4;
  float4 a = *(const float4*)&x[off];
  float4 b = *(const float4*)&p[off];
  float4 c = *(const float4*)&p[2097152 + off];
  float4 v = {a.x + b.x + c.x, a.y + b.y + c.y, a.z + b.z + c.z, a.w + b.w + c.w};
  *(float4*)&x2[off] = v;
  float ss = v.x * v.x + v.y * v.y + v.z * v.z + v.w * v.w;
#pragma unroll
  for (int m = 1; m < 64; m <<= 1) ss += __shfl_xor(ss, m);
  __shared__ float ws_[4];
  if ((t & 63) == 0) ws_[t >> 6] = ss;
  __syncthreads();
  float tot = ws_[0] + ws_[1] + ws_[2] + ws_[3];
  float scale = rsqrtf(tot * (1.0f / 1024.0f) + 1e-6f);
  ushort4 o;
  o.x = f2bf(v.x * scale * w[t * 4 + 0]);
  o.y = f2bf(v.y * scale * w[t * 4 + 1]);
  o.z = f2bf(v.z * scale * w[t * 4 + 2]);
  o.w = f2bf(v.w * scale * w[t * 4 + 3]);
  *(ushort4*)&outbf[off] = o;
}

// out = x2 + p0 + p1  (split-K reduce for ffn_down). 2048 blocks x 256.
__global__ void final_add(const float* __restrict__ x2, const float* __restrict__ p,
                          float* __restrict__ out) {
  int i = blockIdx.x * 256 + threadIdx.x;
  float4 a = ((const float4*)x2)[i];
  float4 b = ((const float4*)p)[i];
  float4 c = ((const float4*)(p + 2097152))[i];
  float4 o = {a.x + b.x + c.x, a.y + b.y + c.y, a.z + b.z + c.z, a.w + b.w + c.w};
  ((float4*)out)[i] = o;
}

// ---------------------------------------------------------------------------
// bf16 MFMA GEMM, C = A @ W^T. 128x128 tile, BK=32.
// Double-buffered LDS: stage(kt+1) issued before compute(kt); ONE barrier/iter.
// XOR bank swizzle: 16B chunk q of row r lives at slot r*4 + (q ^ ((r>>1)&3)).
// MAP 0: (bn,bm)=(x,y).          MAP 1: dt+xproj (extra block-row in y).
// MAP 2: 1D swizzle for 44 cols. MAP 3: split-K x2 (x = bn(0..7) + 8*ks).
// EPI 0: bf16 store. EPI 1: softplus(acc+aux[gc]) / xproj->C2. EPI 3: fp32
// partial store at Cv + ks*2048*1024.
// ---------------------------------------------------------------------------
template <int EPI, int MAP>
__global__ __launch_bounds__(256, 4) void gemm_bt(
    const unsigned short* __restrict__ A,
    const unsigned short* __restrict__ W1,
    const unsigned short* __restrict__ W2,
    int n1_blocks, int ncols, int K,
    void* __restrict__ Cv, int ldc,
    const float* __restrict__ aux,
    float* __restrict__ C2) {
  __shared__ __align__(16) unsigned short As[2][BM * BK];
  __shared__ __align__(16) unsigned short Bs[2][BN * BK];
  int bn, bm, ks = 0, k0 = 0, kend = K;
  if (MAP == 0) {
    bn = blockIdx.x; bm = blockIdx.y;
  } else if (MAP == 1) {
    if (blockIdx.y < gridDim.y - 1) { bn = blockIdx.x; bm = blockIdx.y; }
    else                            { bn = n1_blocks;  bm = blockIdx.x; }
  } else if (MAP == 2) {
    int l = blockIdx.x, i = l >> 3;
    bn = (l & 7) + 8 * (i % 6);
    bm = i / 6;
    if (bn >= ncols) return;
  } else {  // MAP 3: split-K x2
    bn = blockIdx.x & 7; bm = blockIdx.y;
    ks = blockIdx.x >> 3;
    int half = (K / 64) * 32;
    k0 = ks * half;
    kend = ks ? K : half;
  }
  const int tid = threadIdx.x;
  const int wave = tid >> 6, lane = tid & 63;
  const unsigned short* W;
  int wrow0;
  if (bn < n1_blocks) { W = W1; wrow0 = bn * BN; }
  else                { W = W2; wrow0 = (bn - n1_blocks) * BN; }
  const int m0 = bm * BM;
  const int wm = wave >> 1, wn = wave & 1;
  const int l15 = lane & 15, quad = lane >> 4;

  floatx4 acc[4][4] = {};

  // staging: thread owns LDS slots c0, c1 (16B each); slot c holds row r=c>>2,
  // swizzled chunk q = (c&3) ^ ((r>>1)&3).
  const int c0 = wave * 64 + lane;
  const int r0 = c0 >> 2, k0off = ((c0 & 3) ^ ((r0 >> 1) & 3)) * 8;
  const int c1 = c0 + 256;
  const int r1 = c1 >> 2, k1off = ((c1 & 3) ^ ((r1 >> 1) & 3)) * 8;

  auto stage = [&](int kb, int buf) {
    async_copy16(A + (size_t)(m0 + r0) * K + kb + k0off, &As[buf][c0 * 8]);
    async_copy16(A + (size_t)(m0 + r1) * K + kb + k1off, &As[buf][c1 * 8]);
    async_copy16(W + (size_t)(wrow0 + r0) * K + kb + k0off, &Bs[buf][c0 * 8]);
    async_copy16(W + (size_t)(wrow0 + r1) * K + kb + k1off, &Bs[buf][c1 * 8]);
  };

  const int nk = (kend - k0) / BK;
  stage(k0, 0);
  for (int kt = 0; kt < nk; ++kt) {
    const int cur = kt & 1;
    __syncthreads();                 // stage(kt) done; prev reads drained
    if (kt + 1 < nk) stage(k0 + (kt + 1) * BK, cur ^ 1);

    short8 af[4], bf4[4];
#pragma unroll
    for (int i = 0; i < 4; ++i) {
      int row = wm * 64 + i * 16 + l15;
      af[i] = *(const short8*)&As[cur][(row * 4 + (quad ^ ((row >> 1) & 3))) * 8];
    }
#pragma unroll
    for (int j = 0; j < 4; ++j) {
      int row = wn * 64 + j * 16 + l15;
      bf4[j] = *(const short8*)&Bs[cur][(row * 4 + (quad ^ ((row >> 1) & 3))) * 8];
    }
#pragma unroll
    for (int i = 0; i < 4; ++i)
#pragma unroll
      for (int j = 0; j < 4; ++j)
        acc[i][j] = __builtin_amdgcn_mfma_f32_16x16x32_bf16(af[i], bf4[j], acc[i][j], 0, 0, 0);
  }

  const bool alt = (EPI == 1) && (bn >= n1_blocks);
#pragma unroll
  for (int i = 0; i < 4; ++i)
#pragma unroll
    for (int j = 0; j < 4; ++j)
#pragma unroll
      for (int r = 0; r < 4; ++r) {
        int gr = m0 + wm * 64 + i * 16 + quad * 4 + r;
        int lc = wn * 64 + j * 16 + l15;
        int gc = bn * BN + lc;
        float v = acc[i][j][r];
        if (EPI == 0) {
          ((unsigned short*)Cv)[(size_t)gr * ldc + gc] = f2bf(v);
        } else if (EPI == 1) {
          if (alt) {
            C2[(size_t)gr * 128 + lc] = v;
          } else {
            v += aux[gc];
            v = fmaxf(v, 0.0f) + log1pf(__expf(-fabsf(v)));
            ((float*)Cv)[(size_t)gr * ldc + gc] = v;
          }
        } else {  // EPI 3: split-K partial
          ((float*)Cv)[(size_t)ks * 2097152 + (size_t)gr * ldc + gc] = v;
        }
      }
}

// ---------------------------------------------------------------------------
// z = z_raw * sigmoid(gate_raw) from bf16 zg [2048][4096]; fp32 + bf16 out.
// ---------------------------------------------------------------------------
__global__ void zfuse(const unsigned short* __restrict__ zg, float* __restrict__ z32,
                      unsigned short* __restrict__ zbf) {
  int i = blockIdx.x * blockDim.x + threadIdx.x;
  int row = i >> 9, c4 = i & 511;
  ushort4 zr4 = *(const ushort4*)&zg[(size_t)row * 4096 + c4 * 4];
  ushort4 gr4 = *(const ushort4*)&zg[(size_t)row * 4096 + 2048 + c4 * 4];
  float4 o;
  o.x = bf2f(zr4.x) / (1.0f + __expf(-bf2f(gr4.x)));
  o.y = bf2f(zr4.y) / (1.0f + __expf(-bf2f(gr4.y)));
  o.z = bf2f(zr4.z) / (1.0f + __expf(-bf2f(gr4.z)));
  o.w = bf2f(zr4.w) / (1.0f + __expf(-bf2f(gr4.w)));
  *(float4*)&z32[(size_t)row * 2048 + c4 * 4] = o;
  ushort4 ob;
  ob.x = f2bf(o.x); ob.y = f2bf(o.y); ob.z = f2bf(o.z); ob.w = f2bf(o.w);
  *(ushort4*)&zbf[(size_t)row * 2048 + c4 * 4] = ob;
}

// ---------------------------------------------------------------------------
// Chunked selective scan. T=1024 = 32 chunks x 32 steps.
// bc128: [2048][128] rows = (b*1024+t), cols 0..15 = B, 16..31 = C.
// ---------------------------------------------------------------------------
__device__ __forceinline__ void stage_bc(const float* __restrict__ bc128,
                                         int b, int c, float* bcs, int tid) {
  int row = tid >> 3, c4 = tid & 7;
  const float* src = bc128 + ((size_t)b * 1024 + c * 32 + row) * 128 + c4 * 4;
  *(float4*)&bcs[row * 32 + c4 * 4] = *(const float4*)src;
}

__global__ __launch_bounds__(256) void scan_phase1(
    const float* __restrict__ dt, const float* __restrict__ z,
    const float* __restrict__ bc128, const float* __restrict__ A_log,
    float* __restrict__ P, float* __restrict__ S) {
  const int d = blockIdx.x * 256 + threadIdx.x;
  const int c = blockIdx.y, b = blockIdx.z;
  __shared__ float bcs[1024];
  stage_bc(bc128, b, c, bcs, threadIdx.x);
  __syncthreads();
  float A2[16];
#pragma unroll
  for (int n = 0; n < 16; ++n) A2[n] = -__expf(A_log[d * 16 + n]) * 1.44269504f;
  float p[16], s[16];
#pragma unroll
  for (int n = 0; n < 16; ++n) { p[n] = 1.0f; s[n] = 0.0f; }
  const size_t base = ((size_t)b * 1024 + c * 32) * 2048 + d;
#pragma unroll 4
  for (int t = 0; t < 32; ++t) {
    float dtv = dt[base + (size_t)t * 2048];
    float zv  = z [base + (size_t)t * 2048];
    float dtz = dtv * zv;
#pragma unroll
    for (int n = 0; n < 16; ++n) {
      float dA = exp2f(dtv * A2[n]);
      s[n] = __builtin_fmaf(dA, s[n], dtz * bcs[t * 32 + n]);
      p[n] *= dA;
    }
  }
  float* Pp = P + (((size_t)c * 2 + b) * 2048 + d) * 16;
  float* Sp = S + (((size_t)c * 2 + b) * 2048 + d) * 16;
#pragma unroll
  for (int n = 0; n < 16; ++n) { Pp[n] = p[n]; Sp[n] = s[n]; }
}

__global__ __launch_bounds__(256) void scan_phase2(
    const float* __restrict__ P, const float* __restrict__ S,
    float* __restrict__ H) {
  int i = blockIdx.x * 256 + threadIdx.x;
  float h = 0.0f;
#pragma unroll
  for (int c = 0; c < 32; ++c) {
    size_t idx = (size_t)c * 65536 + i;
    H[idx] = h;
    h = __builtin_fmaf(P[idx], h, S[idx]);
  }
}

__global__ __launch_bounds__(256) void scan_phase3(
    const float* __restrict__ dt, const float* __restrict__ z,
    const float* __restrict__ bc128, const float* __restrict__ A_log,
    const float* __restrict__ Dp, const float* __restrict__ H,
    unsigned short* __restrict__ ybf) {
  const int d = blockIdx.x * 256 + threadIdx.x;
  const int c = blockIdx.y, b = blockIdx.z;
  __shared__ float bcs[1024];
  stage_bc(bc128, b, c, bcs, threadIdx.x);
  __syncthreads();
  float A2[16];
#pragma unroll
  for (int n = 0; n < 16; ++n) A2[n] = -__expf(A_log[d * 16 + n]) * 1.44269504f;
  float h[16];
  const float* Hp = H + (((size_t)c * 2 + b) * 2048 + d) * 16;
#pragma unroll
  for (int n = 0; n < 16; ++n) h[n] = Hp[n];
  const float Dd = Dp[d];
  const size_t base = ((size_t)b * 1024 + c * 32) * 2048 + d;
#pragma unroll 4
  for (int t = 0; t < 32; ++t) {
    float dtv = dt[base + (size_t)t * 2048];
    float zv  = z [base + (size_t)t * 2048];
    float dtz = dtv * zv;
    float y = zv * Dd;
#pragma unroll
    for (int n = 0; n < 16; ++n) {
      float dA = exp2f(dtv * A2[n]);
      h[n] = __builtin_fmaf(dA, h[n], dtz * bcs[t * 32 + n]);
      y = __builtin_fmaf(h[n], bcs[t * 32 + 16 + n], y);
    }
    ybf[base + (size_t)t * 2048] = f2bf(y);
  }
}

// ---------------------------------------------------------------------------
// act = silu(g) * u from bf16 gu buffer [2048][5632].
// ---------------------------------------------------------------------------
__global__ void actfuse(const unsigned short* __restrict__ gu,
                        unsigned short* __restrict__ act) {
  int i = blockIdx.x * blockDim.x + threadIdx.x;
  int row = i / 688, c4 = i - row * 688;
  ushort4 g4 = *(const ushort4*)&gu[(size_t)row * 5632 + c4 * 4];
  ushort4 u4 = *(const ushort4*)&gu[(size_t)row * 5632 + 2816 + c4 * 4];
  float gx = bf2f(g4.x), gy = bf2f(g4.y), gz = bf2f(g4.z), gw = bf2f(g4.w);
  ushort4 o;
  o.x = f2bf(gx / (1.0f + __expf(-gx)) * bf2f(u4.x));
  o.y = f2bf(gy / (1.0f + __expf(-gy)) * bf2f(u4.y));
  o.z = f2bf(gz / (1.0f + __expf(-gz)) * bf2f(u4.z));
  o.w = f2bf(gw / (1.0f + __expf(-gw)) * bf2f(u4.w));
  *(ushort4*)&act[(size_t)row * 2752 + c4 * 4] = o;
}

// ---------------------------------------------------------------------------
extern "C" void kernel_launch(void* const* d_in, const int* in_sizes, int n_in,
                              void* d_out, int out_size, void* d_ws, size_t ws_size,
                              hipStream_t stream) {
  const float* x         = (const float*)d_in[0];
  const float* norm1_w   = (const float*)d_in[1];
  const float* in_proj_w = (const float*)d_in[2];
  const float* gate_w    = (const float*)d_in[3];
  const float* dt_w      = (const float*)d_in[4];
  const float* dt_b      = (const float*)d_in[5];
  const float* x_proj_w  = (const float*)d_in[6];
  const float* A_log     = (const float*)d_in[7];
  const float* Dp        = (const float*)d_in[8];
  const float* out_w     = (const float*)d_in[9];
  const float* ffn_nw    = (const float*)d_in[10];
  const float* ffn_g     = (const float*)d_in[11];
  const float* ffn_u     = (const float*)d_in[12];
  const float* ffn_d     = (const float*)d_in[13];
  float* out = (float*)d_out;

  char* p = (char*)d_ws;
  auto alloc = [&](size_t b) { char* r = p; p += (b + 255) & ~(size_t)255; return r; };
  unsigned short* h_bf   = (unsigned short*)alloc(2048ull * 1024 * 2);
  float* big             = (float*)alloc(2048ull * 5632 * 4);  // zg(bf16)|P,S,H|gu(bf16)
  float* pk              = (float*)alloc(2ull * 2048 * 1024 * 4);  // split-K partials
  float* z32             = (float*)alloc(2048ull * 2048 * 4);
  unsigned short* zbf    = (unsigned short*)alloc(2048ull * 2048 * 2);
  float* dt32            = (float*)alloc(2048ull * 2048 * 4);
  float* bc128           = (float*)alloc(2048ull * 128 * 4);
  unsigned short* ybf    = (unsigned short*)alloc(2048ull * 2048 * 2);
  float* x2              = (float*)alloc(2048ull * 1024 * 4);
  unsigned short* hn_bf  = (unsigned short*)alloc(2048ull * 1024 * 2);
  unsigned short* act_bf = (unsigned short*)alloc(2048ull * 2752 * 2);
  unsigned short* w_in   = (unsigned short*)alloc(2048ull * 1024 * 2);
  unsigned short* w_gate = (unsigned short*)alloc(2048ull * 1024 * 2);
  unsigned short* w_dt   = (unsigned short*)alloc(2048ull * 2048 * 2);
  unsigned short* w_xp   = (unsigned short*)alloc(128ull * 2048 * 2);
  unsigned short* w_out  = (unsigned short*)alloc(1024ull * 2048 * 2);
  unsigned short* w_g    = (unsigned short*)alloc(2816ull * 1024 * 2);
  unsigned short* w_u    = (unsigned short*)alloc(2816ull * 1024 * 2);
  unsigned short* w_d    = (unsigned short*)alloc(1024ull * 2752 * 2);

  unsigned short* zg_bf = (unsigned short*)big;   // [2048][4096] bf16
  unsigned short* gu_bf = (unsigned short*)big;   // [2048][5632] bf16
  float* Pb = big;                                 // scan state (after zfuse)
  float* Sb = big + 2097152;
  float* Hb = big + 4194304;

  auto cvt = [&](const float* s, unsigned short* dst, int rows, int cols, int dst_rows) {
    int ng = dst_rows * (cols / 4);
    cvt_bf16<<<(ng + 255) / 256, 256, 0, stream>>>(s, dst, rows, cols / 4, dst_rows);
  };
  cvt(in_proj_w, w_in, 2048, 1024, 2048);
  cvt(gate_w,    w_gate, 2048, 1024, 2048);
  cvt(dt_w,      w_dt, 2048, 2048, 2048);
  cvt(x_proj_w,  w_xp, 32, 2048, 128);
  cvt(out_w,     w_out, 1024, 2048, 1024);
  cvt(ffn_g,     w_g, 2752, 1024, 2816);
  cvt(ffn_u,     w_u, 2752, 1024, 2816);
  cvt(ffn_d,     w_d, 1024, 2752, 1024);

  // 1) h = rmsnorm(x) -> bf16
  rmsnorm_bf16<<<2048, 256, 0, stream>>>(x, norm1_w, h_bf);
  // 2) zg = h @ [in_proj; gate_proj]^T -> bf16
  gemm_bt<0, 0><<<dim3(32, 16), 256, 0, stream>>>(h_bf, w_in, w_gate, 16, 0, 1024, zg_bf, 4096, nullptr, nullptr);
  // 3) z = z * sigmoid(gate)
  zfuse<<<4096, 256, 0, stream>>>(zg_bf, z32, zbf);
  // 4) dt = softplus(z @ dt_w^T + dt_b) ++ BC = z @ x_proj^T
  gemm_bt<1, 1><<<dim3(16, 17), 256, 0, stream>>>(zbf, w_dt, w_xp, 16, 0, 2048, dt32, 2048, dt_b, bc128);
  // 5) chunked selective scan -> y (bf16)
  scan_phase1<<<dim3(8, 32, 2), 256, 0, stream>>>(dt32, z32, bc128, A_log, Pb, Sb);
  scan_phase2<<<256, 256, 0, stream>>>(Pb, Sb, Hb);
  scan_phase3<<<dim3(8, 32, 2), 256, 0, stream>>>(dt32, z32, bc128, A_log, Dp, Hb, ybf);
  // 6) out_proj split-K x2 -> pk partials
  gemm_bt<3, 3><<<dim3(16, 16), 256, 0, stream>>>(ybf, w_out, w_out, 8, 0, 2048, pk, 1024, nullptr, nullptr);
  // 7) x2 = x + p0 + p1; hn = rmsnorm(x2) -> bf16
  rmsnorm_fuse3<<<2048, 256, 0, stream>>>(x, pk, ffn_nw, x2, hn_bf);
  // 8) gu = hn @ [ffn_gate; ffn_up]^T -> bf16 (swizzled 1D grid)
  gemm_bt<0, 2><<<768, 256, 0, stream>>>(hn_bf, w_g, w_u, 22, 44, 1024, gu_bf, 5632, nullptr, nullptr);
  // 9) act = silu(g) * u -> bf16
  actfuse<<<5504, 256, 0, stream>>>(gu_bf, act_bf);
  // 10) ffn_down split-K x2 -> pk partials
  gemm_bt<3, 3><<<dim3(16, 16), 256, 0, stream>>>(act_bf, w_d, w_d, 8, 0, 2752, pk, 1024, nullptr, nullptr);
  // 11) out = x2 + p0 + p1
  final_add<<<2048, 256, 0, stream>>>(x2, pk, out);
}

// Round 7
// 405.548 us; speedup vs baseline: 1.8876x; 1.0704x over previous
//
#include <hip/hip_runtime.h>
#include <cstdint>
#include <cstddef>

// ---------------------------------------------------------------------------
// Mamba-style prelude block on MI355X (gfx950).
// Round 7: dt GEMM was grid-starved (272 blocks = 1 block/CU -> no cross-
// block barrier overlap -> MfmaUtil 9.5% despite dbuf+swizzle fixing LDS
// conflicts to 0). Fixes:
//  - dt+xproj GEMM split-K x2 via grid z (XCD = x%8 preserved): 544 blocks
//    = 2.1/CU; raw fp32 partials; new dtbc_red applies softplus(p0+p1+b)
//    and sums xproj partials. dt partials reuse `big` (dead in that window).
//  - all 8 weight cvt dispatches merged into one cvt_all (segment table).
// ---------------------------------------------------------------------------

#define BM 128
#define BN 128
#define BK 32

typedef __attribute__((ext_vector_type(8))) short short8;   // 8 bf16 (4 VGPRs)
typedef __attribute__((ext_vector_type(4))) float floatx4;  // 4 fp32 acc

__device__ __forceinline__ unsigned short f2bf(float f) {
  unsigned int u = __builtin_bit_cast(unsigned int, f);
  u = u + 0x7fffu + ((u >> 16) & 1u);   // round-to-nearest-even
  return (unsigned short)(u >> 16);
}
__device__ __forceinline__ float bf2f(unsigned short u) {
  return __builtin_bit_cast(float, (unsigned int)u << 16);
}

__device__ __forceinline__ void async_copy16(const unsigned short* g, unsigned short* l) {
  __builtin_amdgcn_global_load_lds(
      (__attribute__((address_space(1))) void*)(const_cast<unsigned short*>(g)),
      (__attribute__((address_space(3))) void*)(l), 16, 0, 0);
}

// ---------------------------------------------------------------------------
// All weight conversions in ONE dispatch. 8 segments, cumulative group
// offsets precomputed on host (group = 4 floats).
// ---------------------------------------------------------------------------
struct CvtArgs {
  const float* src[8];
  unsigned short* dst[8];
  int rows[8];    // valid source rows (pad rows beyond -> zeros)
  int cols4[8];   // columns / 4
  int g0[9];      // cumulative group offsets
};

__global__ __launch_bounds__(256) void cvt_all(CvtArgs a) {
  int i = blockIdx.x * 256 + threadIdx.x;
  if (i >= a.g0[8]) return;
  int s = 0;
#pragma unroll
  for (int k = 1; k < 8; ++k) s += (i >= a.g0[k]) ? 1 : 0;
  int li = i - a.g0[s];
  int cols4 = a.cols4[s];
  int r = li / cols4, c = li - r * cols4;
  ushort4 o = {0, 0, 0, 0};
  if (r < a.rows[s]) {
    float4 v = *(const float4*)&a.src[s][((size_t)r * cols4 + c) * 4];
    o.x = f2bf(v.x); o.y = f2bf(v.y); o.z = f2bf(v.z); o.w = f2bf(v.w);
  }
  *(ushort4*)&a.dst[s][((size_t)r * cols4 + c) * 4] = o;
}

// ---------------------------------------------------------------------------
// RMSNorm: one block per row of D=1024 fp32, writes bf16.
// ---------------------------------------------------------------------------
__global__ __launch_bounds__(256) void rmsnorm_bf16(
    const float* __restrict__ x, const float* __restrict__ w,
    unsigned short* __restrict__ out) {
  int row = blockIdx.x, t = threadIdx.x;
  float4 v = *(const float4*)&x[(size_t)row * 1024 + t * 4];
  float ss = v.x * v.x + v.y * v.y + v.z * v.z + v.w * v.w;
#pragma unroll
  for (int m = 1; m < 64; m <<= 1) ss += __shfl_xor(ss, m);
  __shared__ float ws_[4];
  if ((t & 63) == 0) ws_[t >> 6] = ss;
  __syncthreads();
  float tot = ws_[0] + ws_[1] + ws_[2] + ws_[3];
  float scale = rsqrtf(tot * (1.0f / 1024.0f) + 1e-6f);
  ushort4 o;
  o.x = f2bf(v.x * scale * w[t * 4 + 0]);
  o.y = f2bf(v.y * scale * w[t * 4 + 1]);
  o.z = f2bf(v.z * scale * w[t * 4 + 2]);
  o.w = f2bf(v.w * scale * w[t * 4 + 3]);
  *(ushort4*)&out[(size_t)row * 1024 + t * 4] = o;
}

// ---------------------------------------------------------------------------
// RMSNorm fused with split-K reduce: x2 = x + p0 + p1; hn = rmsnorm(x2)*w.
// ---------------------------------------------------------------------------
__global__ __launch_bounds__(256) void rmsnorm_fuse3(
    const float* __restrict__ x, const float* __restrict__ p,
    const float* __restrict__ w,
    float* __restrict__ x2, unsigned short* __restrict__ outbf) {
  int row = blockIdx.x, t = threadIdx.x;
  size_t off = (size_t)row * 1024 + t * 4;
  float4 a = *(const float4*)&x[off];
  float4 b = *(const float4*)&p[off];
  float4 c = *(const float4*)&p[2097152 + off];
  float4 v = {a.x + b.x + c.x, a.y + b.y + c.y, a.z + b.z + c.z, a.w + b.w + c.w};
  *(float4*)&x2[off] = v;
  float ss = v.x * v.x + v.y * v.y + v.z * v.z + v.w * v.w;
#pragma unroll
  for (int m = 1; m < 64; m <<= 1) ss += __shfl_xor(ss, m);
  __shared__ float ws_[4];
  if ((t & 63) == 0) ws_[t >> 6] = ss;
  __syncthreads();
  float tot = ws_[0] + ws_[1] + ws_[2] + ws_[3];
  float scale = rsqrtf(tot * (1.0f / 1024.0f) + 1e-6f);
  ushort4 o;
  o.x = f2bf(v.x * scale * w[t * 4 + 0]);
  o.y = f2bf(v.y * scale * w[t * 4 + 1]);
  o.z = f2bf(v.z * scale * w[t * 4 + 2]);
  o.w = f2bf(v.w * scale * w[t * 4 + 3]);
  *(ushort4*)&outbf[off] = o;
}

// out = x2 + p0 + p1  (split-K reduce for ffn_down).
__global__ void final_add(const float* __restrict__ x2, const float* __restrict__ p,
                          float* __restrict__ out) {
  int i = blockIdx.x * 256 + threadIdx.x;
  float4 a = ((const float4*)x2)[i];
  float4 b = ((const float4*)p)[i];
  float4 c = ((const float4*)(p + 2097152))[i];
  float4 o = {a.x + b.x + c.x, a.y + b.y + c.y, a.z + b.z + c.z, a.w + b.w + c.w};
  ((float4*)out)[i] = o;
}

// dt32 = softplus(pd0 + pd1 + dt_b[col]);  bc128 = pb0 + pb1.
__global__ __launch_bounds__(256) void dtbc_red(
    const float* __restrict__ pd, const float* __restrict__ pb,
    const float* __restrict__ dtb, float* __restrict__ dt32,
    float* __restrict__ bc128) {
  int bi = blockIdx.x, t = threadIdx.x;
  if (bi < 4096) {                       // dt: 2048 x 512 float4 groups
    int i = bi * 256 + t;
    int c4 = i & 511;
    size_t off = (size_t)i * 4;
    float4 a = *(const float4*)&pd[off];
    float4 b = *(const float4*)&pd[4194304ull + off];
    float4 g = *(const float4*)&dtb[c4 * 4];
    float4 v = {a.x + b.x + g.x, a.y + b.y + g.y, a.z + b.z + g.z, a.w + b.w + g.w};
    float4 o;
    o.x = fmaxf(v.x, 0.0f) + log1pf(__expf(-fabsf(v.x)));
    o.y = fmaxf(v.y, 0.0f) + log1pf(__expf(-fabsf(v.y)));
    o.z = fmaxf(v.z, 0.0f) + log1pf(__expf(-fabsf(v.z)));
    o.w = fmaxf(v.w, 0.0f) + log1pf(__expf(-fabsf(v.w)));
    *(float4*)&dt32[off] = o;
  } else {                               // bc: 2048 x 32 float4 groups
    int i = (bi - 4096) * 256 + t;
    size_t off = (size_t)i * 4;
    float4 a = *(const float4*)&pb[off];
    float4 b = *(const float4*)&pb[262144ull + off];
    float4 o = {a.x + b.x, a.y + b.y, a.z + b.z, a.w + b.w};
    *(float4*)&bc128[off] = o;
  }
}

// ---------------------------------------------------------------------------
// bf16 MFMA GEMM, C = A @ W^T. 128x128 tile, BK=32.
// Double-buffered LDS (one barrier/iter) + XOR bank swizzle (conflict-free).
// MAP 0: (bn,bm)=(x,y).
// MAP 2: 1D swizzle for 44 cols: bn=(l&7)+8*((l>>3)%6), bm=(l>>3)/6.
// MAP 3: split-K x2 in x: bn=x&7, ks=x>>3.
// MAP 4: dt+xproj split-K x2: (x,y) as MAP1 (y==last -> xproj row), ks=z.
// EPI 0: bf16 store. EPI 3: fp32 partial at +ks*2048*1024.
// EPI 4: dt partial at +ks*2048*2048 / xproj partial at C2+ks*2048*128.
// ---------------------------------------------------------------------------
template <int EPI, int MAP>
__global__ __launch_bounds__(256, 4) void gemm_bt(
    const unsigned short* __restrict__ A,
    const unsigned short* __restrict__ W1,
    const unsigned short* __restrict__ W2,
    int n1_blocks, int ncols, int K,
    void* __restrict__ Cv, int ldc,
    float* __restrict__ C2) {
  __shared__ __align__(16) unsigned short As[2][BM * BK];
  __shared__ __align__(16) unsigned short Bs[2][BN * BK];
  int bn, bm, ks = 0, k0 = 0, kend = K;
  if (MAP == 0) {
    bn = blockIdx.x; bm = blockIdx.y;
  } else if (MAP == 2) {
    int l = blockIdx.x, i = l >> 3;
    bn = (l & 7) + 8 * (i % 6);
    bm = i / 6;
    if (bn >= ncols) return;
  } else if (MAP == 3) {
    bn = blockIdx.x & 7; bm = blockIdx.y;
    ks = blockIdx.x >> 3;
    int half = (K / 64) * 32;
    k0 = ks * half;
    kend = ks ? K : half;
  } else {  // MAP 4
    if ((int)blockIdx.y < gridDim.y - 1) { bn = blockIdx.x; bm = blockIdx.y; }
    else                                 { bn = n1_blocks;  bm = blockIdx.x; }
    ks = blockIdx.z;
    k0 = ks * (K >> 1);
    kend = k0 + (K >> 1);
  }
  const int tid = threadIdx.x;
  const int wave = tid >> 6, lane = tid & 63;
  const unsigned short* W;
  int wrow0;
  if (bn < n1_blocks) { W = W1; wrow0 = bn * BN; }
  else                { W = W2; wrow0 = (bn - n1_blocks) * BN; }
  const int m0 = bm * BM;
  const int wm = wave >> 1, wn = wave & 1;
  const int l15 = lane & 15, quad = lane >> 4;

  floatx4 acc[4][4] = {};

  const int c0 = wave * 64 + lane;
  const int r0 = c0 >> 2, k0off = ((c0 & 3) ^ ((r0 >> 1) & 3)) * 8;
  const int c1 = c0 + 256;
  const int r1 = c1 >> 2, k1off = ((c1 & 3) ^ ((r1 >> 1) & 3)) * 8;

  auto stage = [&](int kb, int buf) {
    async_copy16(A + (size_t)(m0 + r0) * K + kb + k0off, &As[buf][c0 * 8]);
    async_copy16(A + (size_t)(m0 + r1) * K + kb + k1off, &As[buf][c1 * 8]);
    async_copy16(W + (size_t)(wrow0 + r0) * K + kb + k0off, &Bs[buf][c0 * 8]);
    async_copy16(W + (size_t)(wrow0 + r1) * K + kb + k1off, &Bs[buf][c1 * 8]);
  };

  const int nk = (kend - k0) / BK;
  stage(k0, 0);
  for (int kt = 0; kt < nk; ++kt) {
    const int cur = kt & 1;
    __syncthreads();
    if (kt + 1 < nk) stage(k0 + (kt + 1) * BK, cur ^ 1);

    short8 af[4], bf4[4];
#pragma unroll
    for (int i = 0; i < 4; ++i) {
      int row = wm * 64 + i * 16 + l15;
      af[i] = *(const short8*)&As[cur][(row * 4 + (quad ^ ((row >> 1) & 3))) * 8];
    }
#pragma unroll
    for (int j = 0; j < 4; ++j) {
      int row = wn * 64 + j * 16 + l15;
      bf4[j] = *(const short8*)&Bs[cur][(row * 4 + (quad ^ ((row >> 1) & 3))) * 8];
    }
#pragma unroll
    for (int i = 0; i < 4; ++i)
#pragma unroll
      for (int j = 0; j < 4; ++j)
        acc[i][j] = __builtin_amdgcn_mfma_f32_16x16x32_bf16(af[i], bf4[j], acc[i][j], 0, 0, 0);
  }

#pragma unroll
  for (int i = 0; i < 4; ++i)
#pragma unroll
    for (int j = 0; j < 4; ++j)
#pragma unroll
      for (int r = 0; r < 4; ++r) {
        int gr = m0 + wm * 64 + i * 16 + quad * 4 + r;
        int lc = wn * 64 + j * 16 + l15;
        int gc = bn * BN + lc;
        float v = acc[i][j][r];
        if (EPI == 0) {
          ((unsigned short*)Cv)[(size_t)gr * ldc + gc] = f2bf(v);
        } else if (EPI == 3) {
          ((float*)Cv)[(size_t)ks * 2097152 + (size_t)gr * ldc + gc] = v;
        } else {  // EPI 4
          if (bn < n1_blocks)
            ((float*)Cv)[(size_t)ks * 4194304 + (size_t)gr * ldc + gc] = v;
          else
            C2[(size_t)ks * 262144 + (size_t)gr * 128 + lc] = v;
        }
      }
}

// ---------------------------------------------------------------------------
// z = z_raw * sigmoid(gate_raw) from bf16 zg [2048][4096]; fp32 + bf16 out.
// ---------------------------------------------------------------------------
__global__ void zfuse(const unsigned short* __restrict__ zg, float* __restrict__ z32,
                      unsigned short* __restrict__ zbf) {
  int i = blockIdx.x * blockDim.x + threadIdx.x;
  int row = i >> 9, c4 = i & 511;
  ushort4 zr4 = *(const ushort4*)&zg[(size_t)row * 4096 + c4 * 4];
  ushort4 gr4 = *(const ushort4*)&zg[(size_t)row * 4096 + 2048 + c4 * 4];
  float4 o;
  o.x = bf2f(zr4.x) / (1.0f + __expf(-bf2f(gr4.x)));
  o.y = bf2f(zr4.y) / (1.0f + __expf(-bf2f(gr4.y)));
  o.z = bf2f(zr4.z) / (1.0f + __expf(-bf2f(gr4.z)));
  o.w = bf2f(zr4.w) / (1.0f + __expf(-bf2f(gr4.w)));
  *(float4*)&z32[(size_t)row * 2048 + c4 * 4] = o;
  ushort4 ob;
  ob.x = f2bf(o.x); ob.y = f2bf(o.y); ob.z = f2bf(o.z); ob.w = f2bf(o.w);
  *(ushort4*)&zbf[(size_t)row * 2048 + c4 * 4] = ob;
}

// ---------------------------------------------------------------------------
// Chunked selective scan. T=1024 = 32 chunks x 32 steps.
// ---------------------------------------------------------------------------
__device__ __forceinline__ void stage_bc(const float* __restrict__ bc128,
                                         int b, int c, float* bcs, int tid) {
  int row = tid >> 3, c4 = tid & 7;
  const float* src = bc128 + ((size_t)b * 1024 + c * 32 + row) * 128 + c4 * 4;
  *(float4*)&bcs[row * 32 + c4 * 4] = *(const float4*)src;
}

__global__ __launch_bounds__(256) void scan_phase1(
    const float* __restrict__ dt, const float* __restrict__ z,
    const float* __restrict__ bc128, const float* __restrict__ A_log,
    float* __restrict__ P, float* __restrict__ S) {
  const int d = blockIdx.x * 256 + threadIdx.x;
  const int c = blockIdx.y, b = blockIdx.z;
  __shared__ float bcs[1024];
  stage_bc(bc128, b, c, bcs, threadIdx.x);
  __syncthreads();
  float A2[16];
#pragma unroll
  for (int n = 0; n < 16; ++n) A2[n] = -__expf(A_log[d * 16 + n]) * 1.44269504f;
  float p[16], s[16];
#pragma unroll
  for (int n = 0; n < 16; ++n) { p[n] = 1.0f; s[n] = 0.0f; }
  const size_t base = ((size_t)b * 1024 + c * 32) * 2048 + d;
#pragma unroll 4
  for (int t = 0; t < 32; ++t) {
    float dtv = dt[base + (size_t)t * 2048];
    float zv  = z [base + (size_t)t * 2048];
    float dtz = dtv * zv;
#pragma unroll
    for (int n = 0; n < 16; ++n) {
      float dA = exp2f(dtv * A2[n]);
      s[n] = __builtin_fmaf(dA, s[n], dtz * bcs[t * 32 + n]);
      p[n] *= dA;
    }
  }
  float* Pp = P + (((size_t)c * 2 + b) * 2048 + d) * 16;
  float* Sp = S + (((size_t)c * 2 + b) * 2048 + d) * 16;
#pragma unroll
  for (int n = 0; n < 16; ++n) { Pp[n] = p[n]; Sp[n] = s[n]; }
}

__global__ __launch_bounds__(256) void scan_phase2(
    const float* __restrict__ P, const float* __restrict__ S,
    float* __restrict__ H) {
  int i = blockIdx.x * 256 + threadIdx.x;
  float h = 0.0f;
#pragma unroll
  for (int c = 0; c < 32; ++c) {
    size_t idx = (size_t)c * 65536 + i;
    H[idx] = h;
    h = __builtin_fmaf(P[idx], h, S[idx]);
  }
}

__global__ __launch_bounds__(256) void scan_phase3(
    const float* __restrict__ dt, const float* __restrict__ z,
    const float* __restrict__ bc128, const float* __restrict__ A_log,
    const float* __restrict__ Dp, const float* __restrict__ H,
    unsigned short* __restrict__ ybf) {
  const int d = blockIdx.x * 256 + threadIdx.x;
  const int c = blockIdx.y, b = blockIdx.z;
  __shared__ float bcs[1024];
  stage_bc(bc128, b, c, bcs, threadIdx.x);
  __syncthreads();
  float A2[16];
#pragma unroll
  for (int n = 0; n < 16; ++n) A2[n] = -__expf(A_log[d * 16 + n]) * 1.44269504f;
  float h[16];
  const float* Hp = H + (((size_t)c * 2 + b) * 2048 + d) * 16;
#pragma unroll
  for (int n = 0; n < 16; ++n) h[n] = Hp[n];
  const float Dd = Dp[d];
  const size_t base = ((size_t)b * 1024 + c * 32) * 2048 + d;
#pragma unroll 4
  for (int t = 0; t < 32; ++t) {
    float dtv = dt[base + (size_t)t * 2048];
    float zv  = z [base + (size_t)t * 2048];
    float dtz = dtv * zv;
    float y = zv * Dd;
#pragma unroll
    for (int n = 0; n < 16; ++n) {
      float dA = exp2f(dtv * A2[n]);
      h[n] = __builtin_fmaf(dA, h[n], dtz * bcs[t * 32 + n]);
      y = __builtin_fmaf(h[n], bcs[t * 32 + 16 + n], y);
    }
    ybf[base + (size_t)t * 2048] = f2bf(y);
  }
}

// ---------------------------------------------------------------------------
// act = silu(g) * u from bf16 gu buffer [2048][5632].
// ---------------------------------------------------------------------------
__global__ void actfuse(const unsigned short* __restrict__ gu,
                        unsigned short* __restrict__ act) {
  int i = blockIdx.x * blockDim.x + threadIdx.x;
  int row = i / 688, c4 = i - row * 688;
  ushort4 g4 = *(const ushort4*)&gu[(size_t)row * 5632 + c4 * 4];
  ushort4 u4 = *(const ushort4*)&gu[(size_t)row * 5632 + 2816 + c4 * 4];
  float gx = bf2f(g4.x), gy = bf2f(g4.y), gz = bf2f(g4.z), gw = bf2f(g4.w);
  ushort4 o;
  o.x = f2bf(gx / (1.0f + __expf(-gx)) * bf2f(u4.x));
  o.y = f2bf(gy / (1.0f + __expf(-gy)) * bf2f(u4.y));
  o.z = f2bf(gz / (1.0f + __expf(-gz)) * bf2f(u4.z));
  o.w = f2bf(gw / (1.0f + __expf(-gw)) * bf2f(u4.w));
  *(ushort4*)&act[(size_t)row * 2752 + c4 * 4] = o;
}

// ---------------------------------------------------------------------------
extern "C" void kernel_launch(void* const* d_in, const int* in_sizes, int n_in,
                              void* d_out, int out_size, void* d_ws, size_t ws_size,
                              hipStream_t stream) {
  const float* x         = (const float*)d_in[0];
  const float* norm1_w   = (const float*)d_in[1];
  const float* in_proj_w = (const float*)d_in[2];
  const float* gate_w    = (const float*)d_in[3];
  const float* dt_w      = (const float*)d_in[4];
  const float* dt_b      = (const float*)d_in[5];
  const float* x_proj_w  = (const float*)d_in[6];
  const float* A_log     = (const float*)d_in[7];
  const float* Dp        = (const float*)d_in[8];
  const float* out_w     = (const float*)d_in[9];
  const float* ffn_nw    = (const float*)d_in[10];
  const float* ffn_g     = (const float*)d_in[11];
  const float* ffn_u     = (const float*)d_in[12];
  const float* ffn_d     = (const float*)d_in[13];
  float* out = (float*)d_out;

  char* p = (char*)d_ws;
  auto alloc = [&](size_t b) { char* r = p; p += (b + 255) & ~(size_t)255; return r; };
  unsigned short* h_bf   = (unsigned short*)alloc(2048ull * 1024 * 2);
  float* big             = (float*)alloc(2048ull * 5632 * 4);  // zg(bf16)|dt partials|P,S,H|gu(bf16)
  float* pk              = (float*)alloc(2ull * 2048 * 1024 * 4);  // out/down split-K partials
  float* pkb             = (float*)alloc(2ull * 2048 * 128 * 4);   // xproj split-K partials
  float* z32             = (float*)alloc(2048ull * 2048 * 4);
  unsigned short* zbf    = (unsigned short*)alloc(2048ull * 2048 * 2);
  float* dt32            = (float*)alloc(2048ull * 2048 * 4);
  float* bc128           = (float*)alloc(2048ull * 128 * 4);
  unsigned short* ybf    = (unsigned short*)alloc(2048ull * 2048 * 2);
  float* x2              = (float*)alloc(2048ull * 1024 * 4);
  unsigned short* hn_bf  = (unsigned short*)alloc(2048ull * 1024 * 2);
  unsigned short* act_bf = (unsigned short*)alloc(2048ull * 2752 * 2);
  unsigned short* w_in   = (unsigned short*)alloc(2048ull * 1024 * 2);
  unsigned short* w_gate = (unsigned short*)alloc(2048ull * 1024 * 2);
  unsigned short* w_dt   = (unsigned short*)alloc(2048ull * 2048 * 2);
  unsigned short* w_xp   = (unsigned short*)alloc(128ull * 2048 * 2);
  unsigned short* w_out  = (unsigned short*)alloc(1024ull * 2048 * 2);
  unsigned short* w_g    = (unsigned short*)alloc(2816ull * 1024 * 2);
  unsigned short* w_u    = (unsigned short*)alloc(2816ull * 1024 * 2);
  unsigned short* w_d    = (unsigned short*)alloc(1024ull * 2752 * 2);

  unsigned short* zg_bf = (unsigned short*)big;   // [2048][4096] bf16
  unsigned short* gu_bf = (unsigned short*)big;   // [2048][5632] bf16
  float* pkd = big;                                // dt split-K partials (32 MB)
  float* Pb = big;                                 // scan state (after dtbc_red)
  float* Sb = big + 2097152;
  float* Hb = big + 4194304;

  // --- single conversion dispatch for all 8 weights ---
  CvtArgs ca;
  ca.src[0] = in_proj_w; ca.dst[0] = w_in;   ca.rows[0] = 2048; ca.cols4[0] = 256;
  ca.src[1] = gate_w;    ca.dst[1] = w_gate; ca.rows[1] = 2048; ca.cols4[1] = 256;
  ca.src[2] = dt_w;      ca.dst[2] = w_dt;   ca.rows[2] = 2048; ca.cols4[2] = 512;
  ca.src[3] = x_proj_w;  ca.dst[3] = w_xp;   ca.rows[3] = 32;   ca.cols4[3] = 512;
  ca.src[4] = out_w;     ca.dst[4] = w_out;  ca.rows[4] = 1024; ca.cols4[4] = 512;
  ca.src[5] = ffn_g;     ca.dst[5] = w_g;    ca.rows[5] = 2752; ca.cols4[5] = 256;
  ca.src[6] = ffn_u;     ca.dst[6] = w_u;    ca.rows[6] = 2752; ca.cols4[6] = 256;
  ca.src[7] = ffn_d;     ca.dst[7] = w_d;    ca.rows[7] = 1024; ca.cols4[7] = 688;
  int dstrows[8] = {2048, 2048, 2048, 128, 1024, 2816, 2816, 1024};
  int acc_g = 0;
  for (int s = 0; s < 8; ++s) { ca.g0[s] = acc_g; acc_g += dstrows[s] * ca.cols4[s]; }
  ca.g0[8] = acc_g;  // 4833280 -> 18880 blocks
  cvt_all<<<(acc_g + 255) / 256, 256, 0, stream>>>(ca);

  // 1) h = rmsnorm(x) -> bf16
  rmsnorm_bf16<<<2048, 256, 0, stream>>>(x, norm1_w, h_bf);
  // 2) zg = h @ [in_proj; gate_proj]^T -> bf16
  gemm_bt<0, 0><<<dim3(32, 16), 256, 0, stream>>>(h_bf, w_in, w_gate, 16, 0, 1024, zg_bf, 4096, nullptr);
  // 3) z = z * sigmoid(gate)
  zfuse<<<4096, 256, 0, stream>>>(zg_bf, z32, zbf);
  // 4) dt/xproj GEMM, split-K x2 -> raw partials (pkd in big, pkb)
  gemm_bt<4, 4><<<dim3(16, 17, 2), 256, 0, stream>>>(zbf, w_dt, w_xp, 16, 0, 2048, pkd, 2048, pkb);
  // 5) dt32 = softplus(p0+p1+dt_b); bc128 = q0+q1
  dtbc_red<<<4352, 256, 0, stream>>>(pkd, pkb, dt_b, dt32, bc128);
  // 6) chunked selective scan -> y (bf16)
  scan_phase1<<<dim3(8, 32, 2), 256, 0, stream>>>(dt32, z32, bc128, A_log, Pb, Sb);
  scan_phase2<<<256, 256, 0, stream>>>(Pb, Sb, Hb);
  scan_phase3<<<dim3(8, 32, 2), 256, 0, stream>>>(dt32, z32, bc128, A_log, Dp, Hb, ybf);
  // 7) out_proj split-K x2 -> pk partials
  gemm_bt<3, 3><<<dim3(16, 16), 256, 0, stream>>>(ybf, w_out, w_out, 8, 0, 2048, pk, 1024, nullptr);
  // 8) x2 = x + p0 + p1; hn = rmsnorm(x2) -> bf16
  rmsnorm_fuse3<<<2048, 256, 0, stream>>>(x, pk, ffn_nw, x2, hn_bf);
  // 9) gu = hn @ [ffn_gate; ffn_up]^T -> bf16 (swizzled 1D grid)
  gemm_bt<0, 2><<<768, 256, 0, stream>>>(hn_bf, w_g, w_u, 22, 44, 1024, gu_bf, 5632, nullptr);
  // 10) act = silu(g) * u -> bf16
  actfuse<<<5504, 256, 0, stream>>>(gu_bf, act_bf);
  // 11) ffn_down split-K x2 -> pk partials
  gemm_bt<3, 3><<<dim3(16, 16), 256, 0, stream>>>(act_bf, w_d, w_d, 8, 0, 2752, pk, 1024, nullptr);
  // 12) out = x2 + p0 + p1
  final_add<<<2048, 256, 0, stream>>>(x2, pk, out);
}

// Round 8
// 396.764 us; speedup vs baseline: 1.9294x; 1.0221x over previous
//
#include <hip/hip_runtime.h>
#include <cstdint>
#include <cstddef>

// ---------------------------------------------------------------------------
// Mamba-style prelude block on MI355X (gfx950).
// Round 8: out_proj & ffn_down were still 1 block/CU (256 blocks) -> the
// measured 9.5%-MfmaUtil regime. Split-K x4 (512 blocks ~ 2/CU), 4 fp32
// partials reduced inside rmsnorm_fuse3 / final_add. cvt_all and the first
// rmsnorm merged into one dispatch (block-range split).
// ---------------------------------------------------------------------------

#define BM 128
#define BN 128
#define BK 32

typedef __attribute__((ext_vector_type(8))) short short8;   // 8 bf16 (4 VGPRs)
typedef __attribute__((ext_vector_type(4))) float floatx4;  // 4 fp32 acc

__device__ __forceinline__ unsigned short f2bf(float f) {
  unsigned int u = __builtin_bit_cast(unsigned int, f);
  u = u + 0x7fffu + ((u >> 16) & 1u);   // round-to-nearest-even
  return (unsigned short)(u >> 16);
}
__device__ __forceinline__ float bf2f(unsigned short u) {
  return __builtin_bit_cast(float, (unsigned int)u << 16);
}

__device__ __forceinline__ void async_copy16(const unsigned short* g, unsigned short* l) {
  __builtin_amdgcn_global_load_lds(
      (__attribute__((address_space(1))) void*)(const_cast<unsigned short*>(g)),
      (__attribute__((address_space(3))) void*)(l), 16, 0, 0);
}

// ---------------------------------------------------------------------------
// All weight conversions + first rmsnorm in ONE dispatch.
// Blocks [0, nCvt): bf16 weight conversion (8 segments).
// Blocks [nCvt, nCvt+2048): rmsnorm of x -> h_bf.
// ---------------------------------------------------------------------------
struct CvtArgs {
  const float* src[8];
  unsigned short* dst[8];
  int rows[8];    // valid source rows (pad rows beyond -> zeros)
  int cols4[8];   // columns / 4
  int g0[9];      // cumulative group offsets
};

__global__ __launch_bounds__(256) void cvt_all(
    CvtArgs a, int nCvt,
    const float* __restrict__ x, const float* __restrict__ nw,
    unsigned short* __restrict__ h_bf) {
  __shared__ float ws_[4];
  if ((int)blockIdx.x >= nCvt) {
    int row = blockIdx.x - nCvt, t = threadIdx.x;
    float4 v = *(const float4*)&x[(size_t)row * 1024 + t * 4];
    float ss = v.x * v.x + v.y * v.y + v.z * v.z + v.w * v.w;
#pragma unroll
    for (int m = 1; m < 64; m <<= 1) ss += __shfl_xor(ss, m);
    if ((t & 63) == 0) ws_[t >> 6] = ss;
    __syncthreads();
    float tot = ws_[0] + ws_[1] + ws_[2] + ws_[3];
    float scale = rsqrtf(tot * (1.0f / 1024.0f) + 1e-6f);
    ushort4 o;
    o.x = f2bf(v.x * scale * nw[t * 4 + 0]);
    o.y = f2bf(v.y * scale * nw[t * 4 + 1]);
    o.z = f2bf(v.z * scale * nw[t * 4 + 2]);
    o.w = f2bf(v.w * scale * nw[t * 4 + 3]);
    *(ushort4*)&h_bf[(size_t)row * 1024 + t * 4] = o;
    return;
  }
  int i = blockIdx.x * 256 + threadIdx.x;
  if (i >= a.g0[8]) return;
  int s = 0;
#pragma unroll
  for (int k = 1; k < 8; ++k) s += (i >= a.g0[k]) ? 1 : 0;
  int li = i - a.g0[s];
  int cols4 = a.cols4[s];
  int r = li / cols4, c = li - r * cols4;
  ushort4 o = {0, 0, 0, 0};
  if (r < a.rows[s]) {
    float4 v = *(const float4*)&a.src[s][((size_t)r * cols4 + c) * 4];
    o.x = f2bf(v.x); o.y = f2bf(v.y); o.z = f2bf(v.z); o.w = f2bf(v.w);
  }
  *(ushort4*)&a.dst[s][((size_t)r * cols4 + c) * 4] = o;
}

// ---------------------------------------------------------------------------
// RMSNorm fused with 4-way split-K reduce: x2 = x + p0..p3; hn = rmsnorm(x2).
// ---------------------------------------------------------------------------
__global__ __launch_bounds__(256) void rmsnorm_fuse3(
    const float* __restrict__ x, const float* __restrict__ p,
    const float* __restrict__ w,
    float* __restrict__ x2, unsigned short* __restrict__ outbf) {
  int row = blockIdx.x, t = threadIdx.x;
  size_t off = (size_t)row * 1024 + t * 4;
  float4 a = *(const float4*)&x[off];
  float4 b = *(const float4*)&p[off];
  float4 c = *(const float4*)&p[2097152ull + off];
  float4 d = *(const float4*)&p[4194304ull + off];
  float4 e = *(const float4*)&p[6291456ull + off];
  float4 v = {a.x + b.x + c.x + d.x + e.x, a.y + b.y + c.y + d.y + e.y,
              a.z + b.z + c.z + d.z + e.z, a.w + b.w + c.w + d.w + e.w};
  *(float4*)&x2[off] = v;
  float ss = v.x * v.x + v.y * v.y + v.z * v.z + v.w * v.w;
#pragma unroll
  for (int m = 1; m < 64; m <<= 1) ss += __shfl_xor(ss, m);
  __shared__ float ws_[4];
  if ((t & 63) == 0) ws_[t >> 6] = ss;
  __syncthreads();
  float tot = ws_[0] + ws_[1] + ws_[2] + ws_[3];
  float scale = rsqrtf(tot * (1.0f / 1024.0f) + 1e-6f);
  ushort4 o;
  o.x = f2bf(v.x * scale * w[t * 4 + 0]);
  o.y = f2bf(v.y * scale * w[t * 4 + 1]);
  o.z = f2bf(v.z * scale * w[t * 4 + 2]);
  o.w = f2bf(v.w * scale * w[t * 4 + 3]);
  *(ushort4*)&outbf[off] = o;
}

// out = x2 + p0..p3  (4-way split-K reduce for ffn_down).
__global__ void final_add(const float* __restrict__ x2, const float* __restrict__ p,
                          float* __restrict__ out) {
  int i = blockIdx.x * 256 + threadIdx.x;
  float4 a = ((const float4*)x2)[i];
  float4 b = ((const float4*)p)[i];
  float4 c = ((const float4*)(p + 2097152ull))[i];
  float4 d = ((const float4*)(p + 4194304ull))[i];
  float4 e = ((const float4*)(p + 6291456ull))[i];
  float4 o = {a.x + b.x + c.x + d.x + e.x, a.y + b.y + c.y + d.y + e.y,
              a.z + b.z + c.z + d.z + e.z, a.w + b.w + c.w + d.w + e.w};
  ((float4*)out)[i] = o;
}

// dt32 = softplus(pd0 + pd1 + dt_b[col]);  bc128 = pb0 + pb1.
__global__ __launch_bounds__(256) void dtbc_red(
    const float* __restrict__ pd, const float* __restrict__ pb,
    const float* __restrict__ dtb, float* __restrict__ dt32,
    float* __restrict__ bc128) {
  int bi = blockIdx.x, t = threadIdx.x;
  if (bi < 4096) {                       // dt: 2048 x 512 float4 groups
    int i = bi * 256 + t;
    int c4 = i & 511;
    size_t off = (size_t)i * 4;
    float4 a = *(const float4*)&pd[off];
    float4 b = *(const float4*)&pd[4194304ull + off];
    float4 g = *(const float4*)&dtb[c4 * 4];
    float4 v = {a.x + b.x + g.x, a.y + b.y + g.y, a.z + b.z + g.z, a.w + b.w + g.w};
    float4 o;
    o.x = fmaxf(v.x, 0.0f) + log1pf(__expf(-fabsf(v.x)));
    o.y = fmaxf(v.y, 0.0f) + log1pf(__expf(-fabsf(v.y)));
    o.z = fmaxf(v.z, 0.0f) + log1pf(__expf(-fabsf(v.z)));
    o.w = fmaxf(v.w, 0.0f) + log1pf(__expf(-fabsf(v.w)));
    *(float4*)&dt32[off] = o;
  } else {                               // bc: 2048 x 32 float4 groups
    int i = (bi - 4096) * 256 + t;
    size_t off = (size_t)i * 4;
    float4 a = *(const float4*)&pb[off];
    float4 b = *(const float4*)&pb[262144ull + off];
    float4 o = {a.x + b.x, a.y + b.y, a.z + b.z, a.w + b.w};
    *(float4*)&bc128[off] = o;
  }
}

// ---------------------------------------------------------------------------
// bf16 MFMA GEMM, C = A @ W^T. 128x128 tile, BK=32.
// Double-buffered LDS (one barrier/iter) + XOR bank swizzle (conflict-free).
// MAP 0: (bn,bm)=(x,y).
// MAP 2: 1D swizzle for 44 cols: bn=(l&7)+8*((l>>3)%6), bm=(l>>3)/6.
// MAP 3: split-K x4 in x: bn=x&7, ks=x>>3 (uneven K-tile split).
// MAP 4: dt+xproj split-K x2: (x,y); y==last -> xproj row; ks=z.
// EPI 0: bf16 store. EPI 3: fp32 partial at +ks*2048*1024.
// EPI 4: dt partial at +ks*2048*2048 / xproj partial at C2+ks*2048*128.
// ---------------------------------------------------------------------------
template <int EPI, int MAP>
__global__ __launch_bounds__(256, 4) void gemm_bt(
    const unsigned short* __restrict__ A,
    const unsigned short* __restrict__ W1,
    const unsigned short* __restrict__ W2,
    int n1_blocks, int ncols, int K,
    void* __restrict__ Cv, int ldc,
    float* __restrict__ C2) {
  __shared__ __align__(16) unsigned short As[2][BM * BK];
  __shared__ __align__(16) unsigned short Bs[2][BN * BK];
  int bn, bm, ks = 0, k0 = 0, nk;
  if (MAP == 0) {
    bn = blockIdx.x; bm = blockIdx.y;
    nk = K / BK;
  } else if (MAP == 2) {
    int l = blockIdx.x, i = l >> 3;
    bn = (l & 7) + 8 * (i % 6);
    bm = i / 6;
    if (bn >= ncols) return;
    nk = K / BK;
  } else if (MAP == 3) {  // split-K x4
    bn = blockIdx.x & 7; bm = blockIdx.y;
    ks = blockIdx.x >> 3;
    int nkt = K / BK, base = nkt >> 2, rem = nkt & 3;
    nk = base + (ks < rem ? 1 : 0);
    int k0t = ks * base + (ks < rem ? ks : rem);
    k0 = k0t * BK;
  } else {  // MAP 4: split-K x2
    if ((int)blockIdx.y < gridDim.y - 1) { bn = blockIdx.x; bm = blockIdx.y; }
    else                                 { bn = n1_blocks;  bm = blockIdx.x; }
    ks = blockIdx.z;
    k0 = ks * (K >> 1);
    nk = (K >> 1) / BK;
  }
  const int tid = threadIdx.x;
  const int wave = tid >> 6, lane = tid & 63;
  const unsigned short* W;
  int wrow0;
  if (bn < n1_blocks) { W = W1; wrow0 = bn * BN; }
  else                { W = W2; wrow0 = (bn - n1_blocks) * BN; }
  const int m0 = bm * BM;
  const int wm = wave >> 1, wn = wave & 1;
  const int l15 = lane & 15, quad = lane >> 4;

  floatx4 acc[4][4] = {};

  const int c0 = wave * 64 + lane;
  const int r0 = c0 >> 2, k0off = ((c0 & 3) ^ ((r0 >> 1) & 3)) * 8;
  const int c1 = c0 + 256;
  const int r1 = c1 >> 2, k1off = ((c1 & 3) ^ ((r1 >> 1) & 3)) * 8;

  auto stage = [&](int kb, int buf) {
    async_copy16(A + (size_t)(m0 + r0) * K + kb + k0off, &As[buf][c0 * 8]);
    async_copy16(A + (size_t)(m0 + r1) * K + kb + k1off, &As[buf][c1 * 8]);
    async_copy16(W + (size_t)(wrow0 + r0) * K + kb + k0off, &Bs[buf][c0 * 8]);
    async_copy16(W + (size_t)(wrow0 + r1) * K + kb + k1off, &Bs[buf][c1 * 8]);
  };

  stage(k0, 0);
  for (int kt = 0; kt < nk; ++kt) {
    const int cur = kt & 1;
    __syncthreads();
    if (kt + 1 < nk) stage(k0 + (kt + 1) * BK, cur ^ 1);

    short8 af[4], bf4[4];
#pragma unroll
    for (int i = 0; i < 4; ++i) {
      int row = wm * 64 + i * 16 + l15;
      af[i] = *(const short8*)&As[cur][(row * 4 + (quad ^ ((row >> 1) & 3))) * 8];
    }
#pragma unroll
    for (int j = 0; j < 4; ++j) {
      int row = wn * 64 + j * 16 + l15;
      bf4[j] = *(const short8*)&Bs[cur][(row * 4 + (quad ^ ((row >> 1) & 3))) * 8];
    }
#pragma unroll
    for (int i = 0; i < 4; ++i)
#pragma unroll
      for (int j = 0; j < 4; ++j)
        acc[i][j] = __builtin_amdgcn_mfma_f32_16x16x32_bf16(af[i], bf4[j], acc[i][j], 0, 0, 0);
  }

#pragma unroll
  for (int i = 0; i < 4; ++i)
#pragma unroll
    for (int j = 0; j < 4; ++j)
#pragma unroll
      for (int r = 0; r < 4; ++r) {
        int gr = m0 + wm * 64 + i * 16 + quad * 4 + r;
        int lc = wn * 64 + j * 16 + l15;
        int gc = bn * BN + lc;
        float v = acc[i][j][r];
        if (EPI == 0) {
          ((unsigned short*)Cv)[(size_t)gr * ldc + gc] = f2bf(v);
        } else if (EPI == 3) {
          ((float*)Cv)[(size_t)ks * 2097152 + (size_t)gr * ldc + gc] = v;
        } else {  // EPI 4
          if (bn < n1_blocks)
            ((float*)Cv)[(size_t)ks * 4194304 + (size_t)gr * ldc + gc] = v;
          else
            C2[(size_t)ks * 262144 + (size_t)gr * 128 + lc] = v;
        }
      }
}

// ---------------------------------------------------------------------------
// z = z_raw * sigmoid(gate_raw) from bf16 zg [2048][4096]; fp32 + bf16 out.
// ---------------------------------------------------------------------------
__global__ void zfuse(const unsigned short* __restrict__ zg, float* __restrict__ z32,
                      unsigned short* __restrict__ zbf) {
  int i = blockIdx.x * blockDim.x + threadIdx.x;
  int row = i >> 9, c4 = i & 511;
  ushort4 zr4 = *(const ushort4*)&zg[(size_t)row * 4096 + c4 * 4];
  ushort4 gr4 = *(const ushort4*)&zg[(size_t)row * 4096 + 2048 + c4 * 4];
  float4 o;
  o.x = bf2f(zr4.x) / (1.0f + __expf(-bf2f(gr4.x)));
  o.y = bf2f(zr4.y) / (1.0f + __expf(-bf2f(gr4.y)));
  o.z = bf2f(zr4.z) / (1.0f + __expf(-bf2f(gr4.z)));
  o.w = bf2f(zr4.w) / (1.0f + __expf(-bf2f(gr4.w)));
  *(float4*)&z32[(size_t)row * 2048 + c4 * 4] = o;
  ushort4 ob;
  ob.x = f2bf(o.x); ob.y = f2bf(o.y); ob.z = f2bf(o.z); ob.w = f2bf(o.w);
  *(ushort4*)&zbf[(size_t)row * 2048 + c4 * 4] = ob;
}

// ---------------------------------------------------------------------------
// Chunked selective scan. T=1024 = 32 chunks x 32 steps.
// ---------------------------------------------------------------------------
__device__ __forceinline__ void stage_bc(const float* __restrict__ bc128,
                                         int b, int c, float* bcs, int tid) {
  int row = tid >> 3, c4 = tid & 7;
  const float* src = bc128 + ((size_t)b * 1024 + c * 32 + row) * 128 + c4 * 4;
  *(float4*)&bcs[row * 32 + c4 * 4] = *(const float4*)src;
}

__global__ __launch_bounds__(256) void scan_phase1(
    const float* __restrict__ dt, const float* __restrict__ z,
    const float* __restrict__ bc128, const float* __restrict__ A_log,
    float* __restrict__ P, float* __restrict__ S) {
  const int d = blockIdx.x * 256 + threadIdx.x;
  const int c = blockIdx.y, b = blockIdx.z;
  __shared__ float bcs[1024];
  stage_bc(bc128, b, c, bcs, threadIdx.x);
  __syncthreads();
  float A2[16];
#pragma unroll
  for (int n = 0; n < 16; ++n) A2[n] = -__expf(A_log[d * 16 + n]) * 1.44269504f;
  float p[16], s[16];
#pragma unroll
  for (int n = 0; n < 16; ++n) { p[n] = 1.0f; s[n] = 0.0f; }
  const size_t base = ((size_t)b * 1024 + c * 32) * 2048 + d;
#pragma unroll 4
  for (int t = 0; t < 32; ++t) {
    float dtv = dt[base + (size_t)t * 2048];
    float zv  = z [base + (size_t)t * 2048];
    float dtz = dtv * zv;
#pragma unroll
    for (int n = 0; n < 16; ++n) {
      float dA = exp2f(dtv * A2[n]);
      s[n] = __builtin_fmaf(dA, s[n], dtz * bcs[t * 32 + n]);
      p[n] *= dA;
    }
  }
  float* Pp = P + (((size_t)c * 2 + b) * 2048 + d) * 16;
  float* Sp = S + (((size_t)c * 2 + b) * 2048 + d) * 16;
#pragma unroll
  for (int n = 0; n < 16; ++n) { Pp[n] = p[n]; Sp[n] = s[n]; }
}

__global__ __launch_bounds__(256) void scan_phase2(
    const float* __restrict__ P, const float* __restrict__ S,
    float* __restrict__ H) {
  int i = blockIdx.x * 256 + threadIdx.x;
  float h = 0.0f;
#pragma unroll
  for (int c = 0; c < 32; ++c) {
    size_t idx = (size_t)c * 65536 + i;
    H[idx] = h;
    h = __builtin_fmaf(P[idx], h, S[idx]);
  }
}

__global__ __launch_bounds__(256) void scan_phase3(
    const float* __restrict__ dt, const float* __restrict__ z,
    const float* __restrict__ bc128, const float* __restrict__ A_log,
    const float* __restrict__ Dp, const float* __restrict__ H,
    unsigned short* __restrict__ ybf) {
  const int d = blockIdx.x * 256 + threadIdx.x;
  const int c = blockIdx.y, b = blockIdx.z;
  __shared__ float bcs[1024];
  stage_bc(bc128, b, c, bcs, threadIdx.x);
  __syncthreads();
  float A2[16];
#pragma unroll
  for (int n = 0; n < 16; ++n) A2[n] = -__expf(A_log[d * 16 + n]) * 1.44269504f;
  float h[16];
  const float* Hp = H + (((size_t)c * 2 + b) * 2048 + d) * 16;
#pragma unroll
  for (int n = 0; n < 16; ++n) h[n] = Hp[n];
  const float Dd = Dp[d];
  const size_t base = ((size_t)b * 1024 + c * 32) * 2048 + d;
#pragma unroll 4
  for (int t = 0; t < 32; ++t) {
    float dtv = dt[base + (size_t)t * 2048];
    float zv  = z [base + (size_t)t * 2048];
    float dtz = dtv * zv;
    float y = zv * Dd;
#pragma unroll
    for (int n = 0; n < 16; ++n) {
      float dA = exp2f(dtv * A2[n]);
      h[n] = __builtin_fmaf(dA, h[n], dtz * bcs[t * 32 + n]);
      y = __builtin_fmaf(h[n], bcs[t * 32 + 16 + n], y);
    }
    ybf[base + (size_t)t * 2048] = f2bf(y);
  }
}

// ---------------------------------------------------------------------------
// act = silu(g) * u from bf16 gu buffer [2048][5632].
// ---------------------------------------------------------------------------
__global__ void actfuse(const unsigned short* __restrict__ gu,
                        unsigned short* __restrict__ act) {
  int i = blockIdx.x * blockDim.x + threadIdx.x;
  int row = i / 688, c4 = i - row * 688;
  ushort4 g4 = *(const ushort4*)&gu[(size_t)row * 5632 + c4 * 4];
  ushort4 u4 = *(const ushort4*)&gu[(size_t)row * 5632 + 2816 + c4 * 4];
  float gx = bf2f(g4.x), gy = bf2f(g4.y), gz = bf2f(g4.z), gw = bf2f(g4.w);
  ushort4 o;
  o.x = f2bf(gx / (1.0f + __expf(-gx)) * bf2f(u4.x));
  o.y = f2bf(gy / (1.0f + __expf(-gy)) * bf2f(u4.y));
  o.z = f2bf(gz / (1.0f + __expf(-gz)) * bf2f(u4.z));
  o.w = f2bf(gw / (1.0f + __expf(-gw)) * bf2f(u4.w));
  *(ushort4*)&act[(size_t)row * 2752 + c4 * 4] = o;
}

// ---------------------------------------------------------------------------
extern "C" void kernel_launch(void* const* d_in, const int* in_sizes, int n_in,
                              void* d_out, int out_size, void* d_ws, size_t ws_size,
                              hipStream_t stream) {
  const float* x         = (const float*)d_in[0];
  const float* norm1_w   = (const float*)d_in[1];
  const float* in_proj_w = (const float*)d_in[2];
  const float* gate_w    = (const float*)d_in[3];
  const float* dt_w      = (const float*)d_in[4];
  const float* dt_b      = (const float*)d_in[5];
  const float* x_proj_w  = (const float*)d_in[6];
  const float* A_log     = (const float*)d_in[7];
  const float* Dp        = (const float*)d_in[8];
  const float* out_w     = (const float*)d_in[9];
  const float* ffn_nw    = (const float*)d_in[10];
  const float* ffn_g     = (const float*)d_in[11];
  const float* ffn_u     = (const float*)d_in[12];
  const float* ffn_d     = (const float*)d_in[13];
  float* out = (float*)d_out;

  char* p = (char*)d_ws;
  auto alloc = [&](size_t b) { char* r = p; p += (b + 255) & ~(size_t)255; return r; };
  unsigned short* h_bf   = (unsigned short*)alloc(2048ull * 1024 * 2);
  float* big             = (float*)alloc(2048ull * 5632 * 4);  // zg(bf16)|dt partials|P,S,H|gu(bf16)
  float* pk              = (float*)alloc(4ull * 2048 * 1024 * 4);  // out/down split-K x4 partials
  float* pkb             = (float*)alloc(2ull * 2048 * 128 * 4);   // xproj split-K partials
  float* z32             = (float*)alloc(2048ull * 2048 * 4);
  unsigned short* zbf    = (unsigned short*)alloc(2048ull * 2048 * 2);
  float* dt32            = (float*)alloc(2048ull * 2048 * 4);
  float* bc128           = (float*)alloc(2048ull * 128 * 4);
  unsigned short* ybf    = (unsigned short*)alloc(2048ull * 2048 * 2);
  float* x2              = (float*)alloc(2048ull * 1024 * 4);
  unsigned short* hn_bf  = (unsigned short*)alloc(2048ull * 1024 * 2);
  unsigned short* act_bf = (unsigned short*)alloc(2048ull * 2752 * 2);
  unsigned short* w_in   = (unsigned short*)alloc(2048ull * 1024 * 2);
  unsigned short* w_gate = (unsigned short*)alloc(2048ull * 1024 * 2);
  unsigned short* w_dt   = (unsigned short*)alloc(2048ull * 2048 * 2);
  unsigned short* w_xp   = (unsigned short*)alloc(128ull * 2048 * 2);
  unsigned short* w_out  = (unsigned short*)alloc(1024ull * 2048 * 2);
  unsigned short* w_g    = (unsigned short*)alloc(2816ull * 1024 * 2);
  unsigned short* w_u    = (unsigned short*)alloc(2816ull * 1024 * 2);
  unsigned short* w_d    = (unsigned short*)alloc(1024ull * 2752 * 2);

  unsigned short* zg_bf = (unsigned short*)big;   // [2048][4096] bf16
  unsigned short* gu_bf = (unsigned short*)big;   // [2048][5632] bf16
  float* pkd = big;                                // dt split-K partials (32 MB)
  float* Pb = big;                                 // scan state (after dtbc_red)
  float* Sb = big + 2097152;
  float* Hb = big + 4194304;

  // --- single dispatch: all 8 weight conversions + rmsnorm(x) ---
  CvtArgs ca;
  ca.src[0] = in_proj_w; ca.dst[0] = w_in;   ca.rows[0] = 2048; ca.cols4[0] = 256;
  ca.src[1] = gate_w;    ca.dst[1] = w_gate; ca.rows[1] = 2048; ca.cols4[1] = 256;
  ca.src[2] = dt_w;      ca.dst[2] = w_dt;   ca.rows[2] = 2048; ca.cols4[2] = 512;
  ca.src[3] = x_proj_w;  ca.dst[3] = w_xp;   ca.rows[3] = 32;   ca.cols4[3] = 512;
  ca.src[4] = out_w;     ca.dst[4] = w_out;  ca.rows[4] = 1024; ca.cols4[4] = 512;
  ca.src[5] = ffn_g;     ca.dst[5] = w_g;    ca.rows[5] = 2752; ca.cols4[5] = 256;
  ca.src[6] = ffn_u;     ca.dst[6] = w_u;    ca.rows[6] = 2752; ca.cols4[6] = 256;
  ca.src[7] = ffn_d;     ca.dst[7] = w_d;    ca.rows[7] = 1024; ca.cols4[7] = 688;
  int dstrows[8] = {2048, 2048, 2048, 128, 1024, 2816, 2816, 1024};
  int acc_g = 0;
  for (int s = 0; s < 8; ++s) { ca.g0[s] = acc_g; acc_g += dstrows[s] * ca.cols4[s]; }
  ca.g0[8] = acc_g;
  int nCvt = (acc_g + 255) / 256;
  cvt_all<<<nCvt + 2048, 256, 0, stream>>>(ca, nCvt, x, norm1_w, h_bf);

  // 2) zg = h @ [in_proj; gate_proj]^T -> bf16
  gemm_bt<0, 0><<<dim3(32, 16), 256, 0, stream>>>(h_bf, w_in, w_gate, 16, 0, 1024, zg_bf, 4096, nullptr);
  // 3) z = z * sigmoid(gate)
  zfuse<<<4096, 256, 0, stream>>>(zg_bf, z32, zbf);
  // 4) dt/xproj GEMM, split-K x2 -> raw partials (pkd in big, pkb)
  gemm_bt<4, 4><<<dim3(16, 17, 2), 256, 0, stream>>>(zbf, w_dt, w_xp, 16, 0, 2048, pkd, 2048, pkb);
  // 5) dt32 = softplus(p0+p1+dt_b); bc128 = q0+q1
  dtbc_red<<<4352, 256, 0, stream>>>(pkd, pkb, dt_b, dt32, bc128);
  // 6) chunked selective scan -> y (bf16)
  scan_phase1<<<dim3(8, 32, 2), 256, 0, stream>>>(dt32, z32, bc128, A_log, Pb, Sb);
  scan_phase2<<<256, 256, 0, stream>>>(Pb, Sb, Hb);
  scan_phase3<<<dim3(8, 32, 2), 256, 0, stream>>>(dt32, z32, bc128, A_log, Dp, Hb, ybf);
  // 7) out_proj split-K x4 -> pk partials
  gemm_bt<3, 3><<<dim3(32, 16), 256, 0, stream>>>(ybf, w_out, w_out, 8, 0, 2048, pk, 1024, nullptr);
  // 8) x2 = x + p0..p3; hn = rmsnorm(x2) -> bf16
  rmsnorm_fuse3<<<2048, 256, 0, stream>>>(x, pk, ffn_nw, x2, hn_bf);
  // 9) gu = hn @ [ffn_gate; ffn_up]^T -> bf16 (swizzled 1D grid)
  gemm_bt<0, 2><<<768, 256, 0, stream>>>(hn_bf, w_g, w_u, 22, 44, 1024, gu_bf, 5632, nullptr);
  // 10) act = silu(g) * u -> bf16
  actfuse<<<5504, 256, 0, stream>>>(gu_bf, act_bf);
  // 11) ffn_down split-K x4 -> pk partials
  gemm_bt<3, 3><<<dim3(32, 16), 256, 0, stream>>>(act_bf, w_d, w_d, 8, 0, 2752, pk, 1024, nullptr);
  // 12) out = x2 + p0..p3
  final_add<<<2048, 256, 0, stream>>>(x2, pk, out);
}